// Round 5
// baseline (613.317 us; speedup 1.0000x reference)
//
#include <hip/hip_runtime.h>
#include <hip/hip_bf16.h>
#include <math.h>

#define H  128
#define NN 50000
#define EE 800000
#define GG 256
#define NB 196          // ceil(NN/256)

#define PK1 296         // W1T row stride / x row stride (bf16 elems), 268 padded
#define K3 256
#define NSTRIDE 264     // node x-tile LDS row stride
#define ESTRIDE 136     // hidden tile LDS row stride

#define ETILE 128       // edges per tile
#define TILES_PER_BLOCK 25
#define EGRID 250       // 250 * 25 * 128 = 800000

typedef __attribute__((ext_vector_type(8))) short bhalf8;
typedef __attribute__((ext_vector_type(4))) float f32x4;

__device__ __forceinline__ float silu_f(float x) {
    return x / (1.0f + __expf(-x));
}

// fp32 -> bf16 round-to-nearest-even
__device__ __forceinline__ unsigned short f2bf(float x) {
    unsigned int u = __float_as_uint(x);
    unsigned int r = 0x7fffu + ((u >> 16) & 1u);
    return (unsigned short)((u + r) >> 16);
}

// ---- prep kernels ----

__global__ void cvt_nf_kernel(const float* __restrict__ nf, unsigned short* __restrict__ nfb) {
    int idx = blockIdx.x * blockDim.x + threadIdx.x;
    if (idx >= NN * H / 4) return;
    float4 v = *(const float4*)(nf + (size_t)idx * 4);
    ushort4 o;
    o.x = f2bf(v.x); o.y = f2bf(v.y); o.z = f2bf(v.z); o.w = f2bf(v.w);
    *(ushort4*)(nfb + (size_t)idx * 4) = o;
}

__global__ void transpose_w_kernel(const float* __restrict__ W, unsigned short* __restrict__ WT,
                                   int K, int Kpad) {
    int k = blockIdx.x * blockDim.x + threadIdx.x;
    int c = blockIdx.y;
    if (k >= Kpad) return;
    WT[(size_t)c * Kpad + k] = (k < K) ? f2bf(W[(size_t)k * H + c]) : (unsigned short)0;
}

__global__ void lat_kernel(const float* __restrict__ lat, unsigned short* __restrict__ latg) {
    int idx = blockIdx.x * blockDim.x + threadIdx.x;
    if (idx >= GG * 16) return;
    int g = idx >> 4, r = idx & 15;
    float v = 0.0f;
    if (r < 9) {
        int i = r / 3, k = r % 3;
        const float* L = lat + g * 9;
        v = L[i*3+0]*L[k*3+0] + L[i*3+1]*L[k*3+1] + L[i*3+2]*L[k*3+2];
    }
    latg[idx] = f2bf(v);
}

// ---- CSR build ----

__global__ void count_kernel(const int* __restrict__ ei, int* __restrict__ cnt_i) {
    int e = blockIdx.x * blockDim.x + threadIdx.x;
    if (e < EE) atomicAdd(&cnt_i[ei[EE + e]], 1);
}

__global__ void scan1_kernel(const int* __restrict__ cnt_i, int* __restrict__ bsum) {
    __shared__ int red[256];
    int b = blockIdx.x, t = threadIdx.x;
    int n = b * 256 + t;
    red[t] = (n < NN) ? cnt_i[n] : 0;
    __syncthreads();
    for (int s = 128; s > 0; s >>= 1) {
        if (t < s) red[t] += red[t + s];
        __syncthreads();
    }
    if (t == 0) bsum[b] = red[0];
}

__global__ void scan2_kernel(const int* __restrict__ bsum, int* __restrict__ bbase) {
    __shared__ int tmp[256];
    int t = threadIdx.x;
    int c = (t < NB) ? bsum[t] : 0;
    tmp[t] = c;
    __syncthreads();
    for (int s = 1; s < 256; s <<= 1) {
        int u = (t >= s) ? tmp[t - s] : 0;
        __syncthreads();
        tmp[t] += u;
        __syncthreads();
    }
    if (t < NB) bbase[t] = tmp[t] - c;   // exclusive
}

__global__ void scan3_kernel(const int* __restrict__ cnt_i, const int* __restrict__ bbase,
                             int* __restrict__ row_start) {
    __shared__ int tmp[256];
    int b = blockIdx.x, t = threadIdx.x;
    int n = b * 256 + t;
    int c = (n < NN) ? cnt_i[n] : 0;
    tmp[t] = c;
    __syncthreads();
    for (int s = 1; s < 256; s <<= 1) {
        int u = (t >= s) ? tmp[t - s] : 0;
        __syncthreads();
        tmp[t] += u;
        __syncthreads();
    }
    if (n < NN) row_start[n] = bbase[b] + tmp[t] - c;   // exclusive
}

__global__ void scatter_kernel(const int* __restrict__ ei, const int* __restrict__ row_start,
                               int* __restrict__ fill, int* __restrict__ eidx) {
    int e = blockIdx.x * blockDim.x + threadIdx.x;
    if (e < EE) {
        int d = ei[EE + e];
        int pos = row_start[d] + atomicAdd(&fill[d], 1);
        eidx[pos] = e;
    }
}

// ---- edge kernel v2: persistent weights, 128 edges x 128 cols per tile ----
// 4 waves, each owns a 64x64 output subtile. Swapped-operand MFMA:
//   mfma(W_frag(A, idx=col), x_frag(B, idx=row)) -> D[col_sub = lk*4+j][row_sub = lr]
__global__ __launch_bounds__(256, 1) void edge_kernel(
    const unsigned short* __restrict__ nfb, const unsigned short* __restrict__ latg,
    const float* __restrict__ fd,
    const unsigned short* __restrict__ W1T, const float* __restrict__ b1,
    const unsigned short* __restrict__ W2T, const float* __restrict__ b2,
    const int* __restrict__ ei, const int* __restrict__ e2g,
    float* __restrict__ out_edge)
{
    __shared__ unsigned short wlds1[128 * PK1];   // 75776 B, staged once
    __shared__ unsigned short x_s[128 * PK1];     // 75776 B, per tile; e1 overlay
    __shared__ int sIdx[384];                     // src[128] | dst[128] | g[128]

    int tid = threadIdx.x;
    int wid = tid >> 6, lane = tid & 63;
    int wr = wid >> 1, wc = wid & 1;     // wave output subtile: rows wr*64.., cols wc*64..
    int lr = lane & 15, lk = lane >> 4;

    int* sSrc = sIdx;
    int* sDst = sIdx + 128;
    int* sG   = sIdx + 256;

    // ---- stage W1T into LDS once (75776 B linear copy) ----
    {
        const uint4* wsrc = (const uint4*)W1T;
        uint4* wdst = (uint4*)wlds1;
        #pragma unroll
        for (int i = 0; i < 19; ++i) {
            int idx = i * 256 + tid;
            if (idx < 4736) wdst[idx] = wsrc[idx];
        }
    }

    // ---- W2 fragments in registers: w2r[ai][ks], col = wc*64+ai*16+lr ----
    bhalf8 w2r[4][4];
    #pragma unroll
    for (int ai = 0; ai < 4; ++ai)
        #pragma unroll
        for (int ks = 0; ks < 4; ++ks)
            w2r[ai][ks] = *(const bhalf8*)(W2T + (size_t)(wc * 64 + ai * 16 + lr) * H + ks * 32 + lk * 8);

    // bias fragments (col-indexed: j walks cols)
    float4 b1v[4], b2v[4];
    #pragma unroll
    for (int ai = 0; ai < 4; ++ai) {
        b1v[ai] = *(const float4*)(b1 + wc * 64 + ai * 16 + lk * 4);
        b2v[ai] = *(const float4*)(b2 + wc * 64 + ai * 16 + lk * 4);
    }

    unsigned short* e1 = x_s;   // overlay [128][ESTRIDE]

    for (int t = 0; t < TILES_PER_BLOCK; ++t) {
        int eb = (blockIdx.x * TILES_PER_BLOCK + t) * ETILE;

        __syncthreads();   // all threads past prior tile's e1 reads
        if (tid < 128) { sSrc[tid] = ei[eb + tid]; sG[tid] = e2g[eb + tid]; }
        else           { sDst[tid - 128] = ei[EE + eb + (tid - 128)]; }
        __syncthreads();

        // ---- stage x[128][296]: hi|hj cols 0..255 ----
        for (int p = 0; p < 16; ++p) {
            int idx = p * 256 + tid;          // 0..4095
            int r = idx >> 5, c = idx & 31;
            int node = (c < 16) ? sSrc[r] : sDst[r];
            uint4 v = *(const uint4*)(nfb + (size_t)node * H + (c & 15) * 8);
            *(uint4*)(&x_s[r * PK1 + c * 8]) = v;
        }
        // tail cols 256..295: lat(9) fd(3) zeros
        if (tid < 128) {
            int g = sG[tid];
            unsigned short tb[16];
            #pragma unroll
            for (int q = 0; q < 9; ++q) tb[q] = latg[g * 16 + q];
            #pragma unroll
            for (int q = 0; q < 3; ++q) tb[9 + q] = f2bf(fd[(size_t)(eb + tid) * 3 + q]);
            #pragma unroll
            for (int q = 12; q < 16; ++q) tb[q] = 0;
            *(uint4*)(&x_s[tid * PK1 + 256]) = ((uint4*)tb)[0];
            *(uint4*)(&x_s[tid * PK1 + 264]) = ((uint4*)tb)[1];
            uint4 z; z.x = z.y = z.z = z.w = 0;
            *(uint4*)(&x_s[tid * PK1 + 272]) = z;
            *(uint4*)(&x_s[tid * PK1 + 280]) = z;
            *(uint4*)(&x_s[tid * PK1 + 288]) = z;
        }
        __syncthreads();

        // ---- mm1: D1[col][row] = W1T(A) x x(B), 9 k-steps ----
        f32x4 acc1[4][4];
        #pragma unroll
        for (int a = 0; a < 4; ++a)
            #pragma unroll
            for (int b = 0; b < 4; ++b) acc1[a][b] = (f32x4){0.f, 0.f, 0.f, 0.f};

        #pragma unroll
        for (int ks = 0; ks < 9; ++ks) {
            bhalf8 wa[4], xb[4];
            #pragma unroll
            for (int ai = 0; ai < 4; ++ai)
                wa[ai] = *(const bhalf8*)(&wlds1[(wc * 64 + ai * 16 + lr) * PK1 + ks * 32 + lk * 8]);
            #pragma unroll
            for (int bj = 0; bj < 4; ++bj)
                xb[bj] = *(const bhalf8*)(&x_s[(wr * 64 + bj * 16 + lr) * PK1 + ks * 32 + lk * 8]);
            #pragma unroll
            for (int ai = 0; ai < 4; ++ai)
                #pragma unroll
                for (int bj = 0; bj < 4; ++bj)
                    acc1[ai][bj] = __builtin_amdgcn_mfma_f32_16x16x32_bf16(wa[ai], xb[bj], acc1[ai][bj], 0, 0, 0);
        }

        __syncthreads();   // x reads done; safe to overlay e1

        // ---- e1 write: row = wr*64+bj*16+lr, cols = wc*64+ai*16+lk*4 .. +3 ----
        #pragma unroll
        for (int ai = 0; ai < 4; ++ai)
            #pragma unroll
            for (int bj = 0; bj < 4; ++bj) {
                int row = wr * 64 + bj * 16 + lr;
                int colb = wc * 64 + ai * 16 + lk * 4;
                ushort4 pk;
                pk.x = f2bf(silu_f(acc1[ai][bj][0] + b1v[ai].x));
                pk.y = f2bf(silu_f(acc1[ai][bj][1] + b1v[ai].y));
                pk.z = f2bf(silu_f(acc1[ai][bj][2] + b1v[ai].z));
                pk.w = f2bf(silu_f(acc1[ai][bj][3] + b1v[ai].w));
                *(ushort4*)(&e1[row * ESTRIDE + colb]) = pk;
            }
        __syncthreads();

        // ---- mm2: D2[col][row] = W2T(A,regs) x e1(B), 4 k-steps ----
        f32x4 acc2[4][4];
        #pragma unroll
        for (int a = 0; a < 4; ++a)
            #pragma unroll
            for (int b = 0; b < 4; ++b) acc2[a][b] = (f32x4){0.f, 0.f, 0.f, 0.f};

        #pragma unroll
        for (int ks = 0; ks < 4; ++ks) {
            bhalf8 ebf[4];
            #pragma unroll
            for (int bj = 0; bj < 4; ++bj)
                ebf[bj] = *(const bhalf8*)(&e1[(wr * 64 + bj * 16 + lr) * ESTRIDE + ks * 32 + lk * 8]);
            #pragma unroll
            for (int ai = 0; ai < 4; ++ai)
                #pragma unroll
                for (int bj = 0; bj < 4; ++bj)
                    acc2[ai][bj] = __builtin_amdgcn_mfma_f32_16x16x32_bf16(w2r[ai][ks], ebf[bj], acc2[ai][bj], 0, 0, 0);
        }

        // ---- epilogue: coalesced float4 stores ----
        #pragma unroll
        for (int ai = 0; ai < 4; ++ai)
            #pragma unroll
            for (int bj = 0; bj < 4; ++bj) {
                int row = eb + wr * 64 + bj * 16 + lr;
                int colb = wc * 64 + ai * 16 + lk * 4;
                float4 o;
                o.x = silu_f(acc2[ai][bj][0] + b2v[ai].x);
                o.y = silu_f(acc2[ai][bj][1] + b2v[ai].y);
                o.z = silu_f(acc2[ai][bj][2] + b2v[ai].z);
                o.w = silu_f(acc2[ai][bj][3] + b2v[ai].w);
                *(float4*)(&out_edge[(size_t)row * H + colb]) = o;
            }
    }
}

// ---- gather-mean: one wave per node ----
__global__ __launch_bounds__(256) void agg_kernel(
    const float* __restrict__ out_edge, const int* __restrict__ row_start,
    const int* __restrict__ cnt_i, const int* __restrict__ eidx,
    float* __restrict__ agg)
{
    int wid = threadIdx.x >> 6, lane = threadIdx.x & 63;
    int n = blockIdx.x * 4 + wid;
    if (n >= NN) return;
    int start = row_start[n], deg = cnt_i[n];
    float ax = 0.f, ay = 0.f;
    int i = 0;
    for (; i + 2 <= deg; i += 2) {
        int e0 = eidx[start + i], e1 = eidx[start + i + 1];
        float2 v0 = *(const float2*)(out_edge + (size_t)e0 * H + lane * 2);
        float2 v1 = *(const float2*)(out_edge + (size_t)e1 * H + lane * 2);
        ax += v0.x + v1.x; ay += v0.y + v1.y;
    }
    if (i < deg) {
        int e0 = eidx[start + i];
        float2 v0 = *(const float2*)(out_edge + (size_t)e0 * H + lane * 2);
        ax += v0.x; ay += v0.y;
    }
    float inv = 1.0f / fmaxf((float)deg, 1.0f);
    *(float2*)(agg + (size_t)n * H + lane * 2) = make_float2(ax * inv, ay * inv);
}

// ---- node kernel ----
__global__ __launch_bounds__(256) void node_kernel(
    const float* __restrict__ nf, const unsigned short* __restrict__ nfb,
    const float* __restrict__ agg,
    const unsigned short* __restrict__ W3T, const float* __restrict__ b3,
    const unsigned short* __restrict__ W4T, const float* __restrict__ b4,
    float* __restrict__ out0)
{
    __shared__ unsigned short x_lds[64 * NSTRIDE];
    int tid = threadIdx.x;
    int nb = blockIdx.x * 64;

    #pragma unroll
    for (int p = 0; p < 4; ++p) {
        int idx = p * 256 + tid;
        int n = idx >> 4, c = idx & 15;
        int node = nb + n; if (node >= NN) node = NN - 1;
        uint4 v = *(const uint4*)(nfb + (size_t)node * H + c * 8);
        *(uint4*)(&x_lds[n * NSTRIDE + c * 8]) = v;
    }
    #pragma unroll
    for (int p = 0; p < 8; ++p) {
        int idx = p * 256 + tid;
        int n = idx >> 5, c = idx & 31;
        int node = nb + n; if (node >= NN) node = NN - 1;
        float4 s = *(const float4*)(agg + (size_t)node * H + c * 4);
        ushort4 o;
        o.x = f2bf(s.x); o.y = f2bf(s.y); o.z = f2bf(s.z); o.w = f2bf(s.w);
        *(ushort4*)(&x_lds[n * NSTRIDE + 128 + c * 4]) = o;
    }
    __syncthreads();

    int wid = tid >> 6, lane = tid & 63;
    int wr = wid >> 1, wc = wid & 1;
    int lr = lane & 15, lk = lane >> 4;

    f32x4 acc[2][4];
    #pragma unroll
    for (int m = 0; m < 2; ++m)
        #pragma unroll
        for (int n = 0; n < 4; ++n) acc[m][n] = (f32x4){0.f, 0.f, 0.f, 0.f};

    #pragma unroll
    for (int ks = 0; ks < 8; ++ks) {
        bhalf8 a[2], b[4];
        #pragma unroll
        for (int m = 0; m < 2; ++m)
            a[m] = *(const bhalf8*)(&x_lds[(wr * 32 + m * 16 + lr) * NSTRIDE + ks * 32 + lk * 8]);
        #pragma unroll
        for (int n = 0; n < 4; ++n)
            b[n] = *(const bhalf8*)(W3T + (size_t)(wc * 64 + n * 16 + lr) * K3 + ks * 32 + lk * 8);
        #pragma unroll
        for (int m = 0; m < 2; ++m)
            #pragma unroll
            for (int n = 0; n < 4; ++n)
                acc[m][n] = __builtin_amdgcn_mfma_f32_16x16x32_bf16(a[m], b[n], acc[m][n], 0, 0, 0);
    }

    float bn3[4];
    #pragma unroll
    for (int n = 0; n < 4; ++n) bn3[n] = b3[wc * 64 + n * 16 + lr];

    __syncthreads();
    unsigned short* m_lds = x_lds;
    #pragma unroll
    for (int m = 0; m < 2; ++m)
        #pragma unroll
        for (int n = 0; n < 4; ++n)
            #pragma unroll
            for (int j = 0; j < 4; ++j) {
                int row = wr * 32 + m * 16 + lk * 4 + j;
                int col = wc * 64 + n * 16 + lr;
                m_lds[row * ESTRIDE + col] = f2bf(silu_f(acc[m][n][j] + bn3[n]));
            }
    __syncthreads();

    f32x4 acc2[2][4];
    #pragma unroll
    for (int m = 0; m < 2; ++m)
        #pragma unroll
        for (int n = 0; n < 4; ++n) acc2[m][n] = (f32x4){0.f, 0.f, 0.f, 0.f};

    #pragma unroll
    for (int ks = 0; ks < 4; ++ks) {
        bhalf8 a[2], b[4];
        #pragma unroll
        for (int m = 0; m < 2; ++m)
            a[m] = *(const bhalf8*)(&m_lds[(wr * 32 + m * 16 + lr) * ESTRIDE + ks * 32 + lk * 8]);
        #pragma unroll
        for (int n = 0; n < 4; ++n)
            b[n] = *(const bhalf8*)(W4T + (size_t)(wc * 64 + n * 16 + lr) * H + ks * 32 + lk * 8);
        #pragma unroll
        for (int m = 0; m < 2; ++m)
            #pragma unroll
            for (int n = 0; n < 4; ++n)
                acc2[m][n] = __builtin_amdgcn_mfma_f32_16x16x32_bf16(a[m], b[n], acc2[m][n], 0, 0, 0);
    }

    float bn4[4];
    #pragma unroll
    for (int n = 0; n < 4; ++n) bn4[n] = b4[wc * 64 + n * 16 + lr];

    #pragma unroll
    for (int m = 0; m < 2; ++m)
        #pragma unroll
        for (int n = 0; n < 4; ++n)
            #pragma unroll
            for (int j = 0; j < 4; ++j) {
                int row = wr * 32 + m * 16 + lk * 4 + j;
                int col = wc * 64 + n * 16 + lr;
                int node = nb + row;
                if (node < NN) {
                    float base = nf[(size_t)node * H + col];
                    out0[(size_t)node * H + col] = base + silu_f(acc2[m][n][j] + bn4[n]);
                }
            }
}

extern "C" void kernel_launch(void* const* d_in, const int* in_sizes, int n_in,
                              void* d_out, int out_size, void* d_ws, size_t ws_size,
                              hipStream_t stream) {
    const float* nf  = (const float*)d_in[0];
    const float* lat = (const float*)d_in[2];
    const float* fd  = (const float*)d_in[3];
    const float* W1  = (const float*)d_in[4];
    const float* b1  = (const float*)d_in[5];
    const float* W2  = (const float*)d_in[6];
    const float* b2  = (const float*)d_in[7];
    const float* W3  = (const float*)d_in[8];
    const float* b3  = (const float*)d_in[9];
    const float* W4  = (const float*)d_in[10];
    const float* b4  = (const float*)d_in[11];
    const int* ei    = (const int*)d_in[12];
    const int* e2g   = (const int*)d_in[13];

    float* out0     = (float*)d_out;
    float* out_edge = (float*)d_out + (size_t)NN * H;

    char* ws = (char*)d_ws;
    size_t off = 0;
    float* agg = (float*)(ws + off);                    off += (size_t)NN * H * 4;     // 25.6 MB
    int* cnt_i      = (int*)(ws + off);                 off += (size_t)NB * 256 * 4;   // zeroed together
    int* fill       = (int*)(ws + off);                 off += (size_t)NB * 256 * 4;   // with cnt_i
    int* row_start  = (int*)(ws + off);                 off += (size_t)NB * 256 * 4;
    int* bsum       = (int*)(ws + off);                 off += 256 * 4;
    int* bbase      = (int*)(ws + off);                 off += 256 * 4;
    int* eidx       = (int*)(ws + off);                 off += (size_t)EE * 4;         // 3.2 MB
    unsigned short* nfb  = (unsigned short*)(ws + off); off += (size_t)NN * H * 2;     // 12.8 MB
    unsigned short* W1T  = (unsigned short*)(ws + off); off += (size_t)H * PK1 * 2;    // 75.8 KB
    unsigned short* W2T  = (unsigned short*)(ws + off); off += (size_t)H * H * 2;
    unsigned short* W3T  = (unsigned short*)(ws + off); off += (size_t)H * K3 * 2;
    unsigned short* W4T  = (unsigned short*)(ws + off); off += (size_t)H * H * 2;
    unsigned short* latg = (unsigned short*)(ws + off); off += (size_t)GG * 16 * 2;

    // zero cnt_i + fill (adjacent)
    (void)hipMemsetAsync(cnt_i, 0, (size_t)NB * 256 * 4 * 2, stream);

    cvt_nf_kernel<<<(NN * H / 4 + 255) / 256, 256, 0, stream>>>(nf, nfb);
    transpose_w_kernel<<<dim3(2, H), 256, 0, stream>>>(W1, W1T, 268, PK1);
    transpose_w_kernel<<<dim3(1, H), 256, 0, stream>>>(W2, W2T, H, H);
    transpose_w_kernel<<<dim3(1, H), 256, 0, stream>>>(W3, W3T, K3, K3);
    transpose_w_kernel<<<dim3(1, H), 256, 0, stream>>>(W4, W4T, H, H);
    lat_kernel<<<(GG * 16 + 255) / 256, 256, 0, stream>>>(lat, latg);

    // CSR build
    count_kernel<<<(EE + 255) / 256, 256, 0, stream>>>(ei, cnt_i);
    scan1_kernel<<<NB, 256, 0, stream>>>(cnt_i, bsum);
    scan2_kernel<<<1, 256, 0, stream>>>(bsum, bbase);
    scan3_kernel<<<NB, 256, 0, stream>>>(cnt_i, bbase, row_start);
    scatter_kernel<<<(EE + 255) / 256, 256, 0, stream>>>(ei, row_start, fill, eidx);

    edge_kernel<<<EGRID, 256, 0, stream>>>(nfb, latg, fd, W1T, b1, W2T, b2,
                                           ei, e2g, out_edge);
    agg_kernel<<<(NN + 3) / 4, 256, 0, stream>>>(out_edge, row_start, cnt_i, eidx, agg);
    node_kernel<<<(NN + 63) / 64, 256, 0, stream>>>(nf, nfb, agg, W3T, b3, W4T, b4, out0);
}

// Round 6
// 481.315 us; speedup vs baseline: 1.2743x; 1.2743x over previous
//
#include <hip/hip_runtime.h>
#include <hip/hip_bf16.h>
#include <math.h>

#define H  128
#define NN 50000
#define EE 800000
#define GG 256
#define NB 196          // ceil(NN/256)

#define K3 256
#define NSTRIDE 264     // node x-tile LDS row stride
#define ESTRIDE 136     // hidden tile LDS row stride (17*8 -> odd 16B superbank stride)
#define PSTRIDE 136     // p12 staging stride

typedef __attribute__((ext_vector_type(8))) short bhalf8;
typedef __attribute__((ext_vector_type(4))) float f32x4;

__device__ __forceinline__ float silu_f(float x) {
    return x / (1.0f + __expf(-x));
}

// fp32 -> bf16 round-to-nearest-even
__device__ __forceinline__ unsigned short f2bf(float x) {
    unsigned int u = __float_as_uint(x);
    unsigned int r = 0x7fffu + ((u >> 16) & 1u);
    return (unsigned short)((u + r) >> 16);
}

// bf16 bits -> fp32
__device__ __forceinline__ float bf2f(short s) {
    return __uint_as_float(((unsigned int)(unsigned short)s) << 16);
}

// ---- prep kernels ----

// W [K][128] fp32 -> WT [128][Kpad] bf16
__global__ void transpose_w_kernel(const float* __restrict__ W, unsigned short* __restrict__ WT,
                                   int K, int Kpad) {
    int k = blockIdx.x * blockDim.x + threadIdx.x;
    int c = blockIdx.y;
    if (k >= Kpad) return;
    WT[(size_t)c * Kpad + k] = (k < K) ? f2bf(W[(size_t)k * H + c]) : (unsigned short)0;
}

// W12T[j][k]: j<128 -> W1[k][j] (P1 part), j>=128 -> W1[128+k][j-128] (P2 part)
__global__ void w12t_kernel(const float* __restrict__ W1, unsigned short* __restrict__ W12T) {
    int j = blockIdx.x, k = threadIdx.x;   // 256 blocks x 128 threads
    float v = (j < 128) ? W1[(size_t)k * H + j] : W1[(size_t)(128 + k) * H + (j - 128)];
    W12T[(size_t)j * H + k] = f2bf(v);
}

// Q[g][c] = b1[c] + sum_r lat_ips[g][r] * W1[256+r][c]   (bf16 out)
__global__ void q_kernel(const float* __restrict__ lat, const float* __restrict__ W1,
                         const float* __restrict__ b1, unsigned short* __restrict__ Qb) {
    int g = blockIdx.x, c = threadIdx.x;   // 256 x 128
    const float* L = lat + g * 9;
    float q = b1[c];
    #pragma unroll
    for (int i = 0; i < 3; ++i)
        #pragma unroll
        for (int k = 0; k < 3; ++k) {
            float ip = L[i*3+0]*L[k*3+0] + L[i*3+1]*L[k*3+1] + L[i*3+2]*L[k*3+2];
            q += ip * W1[(size_t)(256 + i * 3 + k) * H + c];
        }
    Qb[(size_t)g * H + c] = f2bf(q);
}

// P12[n][0:128] = nf[n] @ W1a ; P12[n][128:256] = nf[n] @ W1b  (bf16 out)
__global__ __launch_bounds__(256) void p12_kernel(
    const float* __restrict__ nf, const unsigned short* __restrict__ W12T,
    unsigned short* __restrict__ P12)
{
    __shared__ unsigned short x_lds[64 * PSTRIDE];
    int tid = threadIdx.x;
    int nb = blockIdx.x * 64;

    #pragma unroll
    for (int p = 0; p < 8; ++p) {
        int idx = p * 256 + tid;
        int n = idx >> 5, c = idx & 31;
        int node = nb + n; if (node >= NN) node = NN - 1;
        float4 v = *(const float4*)(nf + (size_t)node * H + c * 4);
        ushort4 o;
        o.x = f2bf(v.x); o.y = f2bf(v.y); o.z = f2bf(v.z); o.w = f2bf(v.w);
        *(ushort4*)(&x_lds[n * PSTRIDE + c * 4]) = o;
    }
    __syncthreads();

    int wid = tid >> 6, lane = tid & 63;
    int wr = wid & 1, wc = wid >> 1;       // rows wr*32.., cols wc*128..
    int lr = lane & 15, lk = lane >> 4;

    f32x4 acc[2][8];
    #pragma unroll
    for (int m = 0; m < 2; ++m)
        #pragma unroll
        for (int n = 0; n < 8; ++n) acc[m][n] = (f32x4){0.f, 0.f, 0.f, 0.f};

    #pragma unroll
    for (int ks = 0; ks < 4; ++ks) {
        bhalf8 a[2], b[8];
        #pragma unroll
        for (int m = 0; m < 2; ++m)
            a[m] = *(const bhalf8*)(&x_lds[(wr * 32 + m * 16 + lr) * PSTRIDE + ks * 32 + lk * 8]);
        #pragma unroll
        for (int n = 0; n < 8; ++n)
            b[n] = *(const bhalf8*)(W12T + (size_t)(wc * 128 + n * 16 + lr) * H + ks * 32 + lk * 8);
        #pragma unroll
        for (int m = 0; m < 2; ++m)
            #pragma unroll
            for (int n = 0; n < 8; ++n)
                acc[m][n] = __builtin_amdgcn_mfma_f32_16x16x32_bf16(a[m], b[n], acc[m][n], 0, 0, 0);
    }

    #pragma unroll
    for (int m = 0; m < 2; ++m)
        #pragma unroll
        for (int n = 0; n < 8; ++n)
            #pragma unroll
            for (int j = 0; j < 4; ++j) {
                int row = wr * 32 + m * 16 + lk * 4 + j;
                int col = wc * 128 + n * 16 + lr;
                int node = nb + row;
                if (node < NN) P12[(size_t)node * 256 + col] = f2bf(acc[m][n][j]);
            }
}

// ---- CSR build ----

__global__ void count_kernel(const int* __restrict__ ei, int* __restrict__ cnt_i) {
    int e = blockIdx.x * blockDim.x + threadIdx.x;
    if (e < EE) atomicAdd(&cnt_i[ei[EE + e]], 1);
}

__global__ void scan1_kernel(const int* __restrict__ cnt_i, int* __restrict__ bsum) {
    __shared__ int red[256];
    int b = blockIdx.x, t = threadIdx.x;
    int n = b * 256 + t;
    red[t] = (n < NN) ? cnt_i[n] : 0;
    __syncthreads();
    for (int s = 128; s > 0; s >>= 1) {
        if (t < s) red[t] += red[t + s];
        __syncthreads();
    }
    if (t == 0) bsum[b] = red[0];
}

__global__ void scan2_kernel(const int* __restrict__ bsum, int* __restrict__ bbase) {
    __shared__ int tmp[256];
    int t = threadIdx.x;
    int c = (t < NB) ? bsum[t] : 0;
    tmp[t] = c;
    __syncthreads();
    for (int s = 1; s < 256; s <<= 1) {
        int u = (t >= s) ? tmp[t - s] : 0;
        __syncthreads();
        tmp[t] += u;
        __syncthreads();
    }
    if (t < NB) bbase[t] = tmp[t] - c;   // exclusive
}

__global__ void scan3_kernel(const int* __restrict__ cnt_i, const int* __restrict__ bbase,
                             int* __restrict__ row_start) {
    __shared__ int tmp[256];
    int b = blockIdx.x, t = threadIdx.x;
    int n = b * 256 + t;
    int c = (n < NN) ? cnt_i[n] : 0;
    tmp[t] = c;
    __syncthreads();
    for (int s = 1; s < 256; s <<= 1) {
        int u = (t >= s) ? tmp[t - s] : 0;
        __syncthreads();
        tmp[t] += u;
        __syncthreads();
    }
    if (n < NN) row_start[n] = bbase[b] + tmp[t] - c;   // exclusive
}

__global__ void scatter_kernel(const int* __restrict__ ei, const int* __restrict__ row_start,
                               int* __restrict__ fill, int* __restrict__ eidx) {
    int e = blockIdx.x * blockDim.x + threadIdx.x;
    if (e < EE) {
        int d = ei[EE + e];
        int pos = row_start[d] + atomicAdd(&fill[d], 1);
        eidx[pos] = e;
    }
}

// ---- edge kernel v3: gather P1/P2/Q + rank-3 fd term -> silu -> e1 -> mm2 ----
// 128 edges/block, 256 threads, 4 waves. mm2 swapped-operand (verified R5):
//   mfma(W2_frag(A, col via lr), e1_frag(B, row via lr)) -> D[col=lk*4+j][row=lr]
__global__ __launch_bounds__(256) void edge_kernel(
    const unsigned short* __restrict__ P12, const unsigned short* __restrict__ Qb,
    const float* __restrict__ fdg, const float* __restrict__ W1fd,
    const unsigned short* __restrict__ W2T, const float* __restrict__ b2,
    const int* __restrict__ ei, const int* __restrict__ e2g,
    float* __restrict__ out_edge)
{
    __shared__ unsigned short e1[128 * ESTRIDE];   // 34.8 KB
    __shared__ int sSrc[128], sDst[128], sG[128];
    __shared__ float sFd[128 * 3];

    int tid = threadIdx.x;
    int eb = blockIdx.x * 128;

    if (tid < 128) {
        sSrc[tid] = ei[eb + tid];
        sG[tid]   = e2g[eb + tid];
        sFd[tid * 3 + 0] = fdg[(size_t)(eb + tid) * 3 + 0];
        sFd[tid * 3 + 1] = fdg[(size_t)(eb + tid) * 3 + 1];
        sFd[tid * 3 + 2] = fdg[(size_t)(eb + tid) * 3 + 2];
    } else {
        sDst[tid - 128] = ei[EE + eb + (tid - 128)];
    }
    __syncthreads();

    int c = tid & 15;
    // per-lane W1_fd columns (3 rows x 8 cols), L1-cached
    float4 wf[3][2];
    #pragma unroll
    for (int k = 0; k < 3; ++k)
        #pragma unroll
        for (int h = 0; h < 2; ++h)
            wf[k][h] = *(const float4*)(W1fd + k * H + c * 8 + h * 4);

    // ---- build e1[128][128] (bf16) ----
    #pragma unroll
    for (int p = 0; p < 8; ++p) {
        int r = p * 16 + (tid >> 4);
        int src = sSrc[r], dst = sDst[r], g = sG[r];
        bhalf8 p1 = *(const bhalf8*)(P12 + (size_t)src * 256 + c * 8);
        bhalf8 p2 = *(const bhalf8*)(P12 + (size_t)dst * 256 + 128 + c * 8);
        bhalf8 qv = *(const bhalf8*)(Qb + (size_t)g * H + c * 8);
        float f0 = sFd[r * 3 + 0], f1 = sFd[r * 3 + 1], f2v = sFd[r * 3 + 2];
        unsigned int w[4];
        #pragma unroll
        for (int jj = 0; jj < 4; ++jj) {
            unsigned int lo, hi;
            #pragma unroll
            for (int half = 0; half < 2; ++half) {
                int j = jj * 2 + half;
                const float* wfp = (const float*)&wf[0][0];
                float wv0 = wfp[j];          // wf[0][j>>2][j&3]
                float wv1 = wfp[8 + j];      // wf[1]
                float wv2 = wfp[16 + j];     // wf[2]
                float v = bf2f(p1[j]) + bf2f(p2[j]) + bf2f(qv[j])
                        + f0 * wv0 + f1 * wv1 + f2v * wv2;
                unsigned int us = f2bf(silu_f(v));
                if (half == 0) lo = us; else hi = us;
            }
            w[jj] = lo | (hi << 16);
        }
        uint4 pk; pk.x = w[0]; pk.y = w[1]; pk.z = w[2]; pk.w = w[3];
        *(uint4*)(&e1[r * ESTRIDE + c * 8]) = pk;
    }
    __syncthreads();

    // ---- mm2: D2[col][row] = W2T(A) x e1(B), 4 k-steps ----
    int wid = tid >> 6, lane = tid & 63;
    int wr = wid >> 1, wc = wid & 1;   // rows wr*64.., cols wc*64..
    int lr = lane & 15, lk = lane >> 4;

    f32x4 acc2[4][4];
    #pragma unroll
    for (int a = 0; a < 4; ++a)
        #pragma unroll
        for (int b = 0; b < 4; ++b) acc2[a][b] = (f32x4){0.f, 0.f, 0.f, 0.f};

    #pragma unroll
    for (int ks = 0; ks < 4; ++ks) {
        bhalf8 wa[4], xb[4];
        #pragma unroll
        for (int ai = 0; ai < 4; ++ai)
            wa[ai] = *(const bhalf8*)(W2T + (size_t)(wc * 64 + ai * 16 + lr) * H + ks * 32 + lk * 8);
        #pragma unroll
        for (int bj = 0; bj < 4; ++bj)
            xb[bj] = *(const bhalf8*)(&e1[(wr * 64 + bj * 16 + lr) * ESTRIDE + ks * 32 + lk * 8]);
        #pragma unroll
        for (int ai = 0; ai < 4; ++ai)
            #pragma unroll
            for (int bj = 0; bj < 4; ++bj)
                acc2[ai][bj] = __builtin_amdgcn_mfma_f32_16x16x32_bf16(wa[ai], xb[bj], acc2[ai][bj], 0, 0, 0);
    }

    float4 b2v[4];
    #pragma unroll
    for (int ai = 0; ai < 4; ++ai)
        b2v[ai] = *(const float4*)(b2 + wc * 64 + ai * 16 + lk * 4);

    #pragma unroll
    for (int ai = 0; ai < 4; ++ai)
        #pragma unroll
        for (int bj = 0; bj < 4; ++bj) {
            int row = eb + wr * 64 + bj * 16 + lr;
            int colb = wc * 64 + ai * 16 + lk * 4;
            float4 o;
            o.x = silu_f(acc2[ai][bj][0] + b2v[ai].x);
            o.y = silu_f(acc2[ai][bj][1] + b2v[ai].y);
            o.z = silu_f(acc2[ai][bj][2] + b2v[ai].z);
            o.w = silu_f(acc2[ai][bj][3] + b2v[ai].w);
            *(float4*)(&out_edge[(size_t)row * H + colb]) = o;
        }
}

// ---- gather-mean: one wave per node ----
__global__ __launch_bounds__(256) void agg_kernel(
    const float* __restrict__ out_edge, const int* __restrict__ row_start,
    const int* __restrict__ cnt_i, const int* __restrict__ eidx,
    float* __restrict__ agg)
{
    int wid = threadIdx.x >> 6, lane = threadIdx.x & 63;
    int n = blockIdx.x * 4 + wid;
    if (n >= NN) return;
    int start = row_start[n], deg = cnt_i[n];
    float ax = 0.f, ay = 0.f;
    int i = 0;
    for (; i + 2 <= deg; i += 2) {
        int e0 = eidx[start + i], e1 = eidx[start + i + 1];
        float2 v0 = *(const float2*)(out_edge + (size_t)e0 * H + lane * 2);
        float2 v1 = *(const float2*)(out_edge + (size_t)e1 * H + lane * 2);
        ax += v0.x + v1.x; ay += v0.y + v1.y;
    }
    if (i < deg) {
        int e0 = eidx[start + i];
        float2 v0 = *(const float2*)(out_edge + (size_t)e0 * H + lane * 2);
        ax += v0.x; ay += v0.y;
    }
    float inv = 1.0f / fmaxf((float)deg, 1.0f);
    *(float2*)(agg + (size_t)n * H + lane * 2) = make_float2(ax * inv, ay * inv);
}

// ---- node kernel ----
__global__ __launch_bounds__(256) void node_kernel(
    const float* __restrict__ nf, const float* __restrict__ agg,
    const unsigned short* __restrict__ W3T, const float* __restrict__ b3,
    const unsigned short* __restrict__ W4T, const float* __restrict__ b4,
    float* __restrict__ out0)
{
    __shared__ unsigned short x_lds[64 * NSTRIDE];
    int tid = threadIdx.x;
    int nb = blockIdx.x * 64;

    // cols 0..127: nf (fp32 -> bf16)
    #pragma unroll
    for (int p = 0; p < 8; ++p) {
        int idx = p * 256 + tid;
        int n = idx >> 5, c = idx & 31;
        int node = nb + n; if (node >= NN) node = NN - 1;
        float4 v = *(const float4*)(nf + (size_t)node * H + c * 4);
        ushort4 o;
        o.x = f2bf(v.x); o.y = f2bf(v.y); o.z = f2bf(v.z); o.w = f2bf(v.w);
        *(ushort4*)(&x_lds[n * NSTRIDE + c * 4]) = o;
    }
    // cols 128..255: agg
    #pragma unroll
    for (int p = 0; p < 8; ++p) {
        int idx = p * 256 + tid;
        int n = idx >> 5, c = idx & 31;
        int node = nb + n; if (node >= NN) node = NN - 1;
        float4 s = *(const float4*)(agg + (size_t)node * H + c * 4);
        ushort4 o;
        o.x = f2bf(s.x); o.y = f2bf(s.y); o.z = f2bf(s.z); o.w = f2bf(s.w);
        *(ushort4*)(&x_lds[n * NSTRIDE + 128 + c * 4]) = o;
    }
    __syncthreads();

    int wid = tid >> 6, lane = tid & 63;
    int wr = wid >> 1, wc = wid & 1;
    int lr = lane & 15, lk = lane >> 4;

    f32x4 acc[2][4];
    #pragma unroll
    for (int m = 0; m < 2; ++m)
        #pragma unroll
        for (int n = 0; n < 4; ++n) acc[m][n] = (f32x4){0.f, 0.f, 0.f, 0.f};

    #pragma unroll
    for (int ks = 0; ks < 8; ++ks) {
        bhalf8 a[2], b[4];
        #pragma unroll
        for (int m = 0; m < 2; ++m)
            a[m] = *(const bhalf8*)(&x_lds[(wr * 32 + m * 16 + lr) * NSTRIDE + ks * 32 + lk * 8]);
        #pragma unroll
        for (int n = 0; n < 4; ++n)
            b[n] = *(const bhalf8*)(W3T + (size_t)(wc * 64 + n * 16 + lr) * K3 + ks * 32 + lk * 8);
        #pragma unroll
        for (int m = 0; m < 2; ++m)
            #pragma unroll
            for (int n = 0; n < 4; ++n)
                acc[m][n] = __builtin_amdgcn_mfma_f32_16x16x32_bf16(a[m], b[n], acc[m][n], 0, 0, 0);
    }

    float bn3[4];
    #pragma unroll
    for (int n = 0; n < 4; ++n) bn3[n] = b3[wc * 64 + n * 16 + lr];

    __syncthreads();
    unsigned short* m_lds = x_lds;
    #pragma unroll
    for (int m = 0; m < 2; ++m)
        #pragma unroll
        for (int n = 0; n < 4; ++n)
            #pragma unroll
            for (int j = 0; j < 4; ++j) {
                int row = wr * 32 + m * 16 + lk * 4 + j;
                int col = wc * 64 + n * 16 + lr;
                m_lds[row * ESTRIDE + col] = f2bf(silu_f(acc[m][n][j] + bn3[n]));
            }
    __syncthreads();

    f32x4 acc2[2][4];
    #pragma unroll
    for (int m = 0; m < 2; ++m)
        #pragma unroll
        for (int n = 0; n < 4; ++n) acc2[m][n] = (f32x4){0.f, 0.f, 0.f, 0.f};

    #pragma unroll
    for (int ks = 0; ks < 4; ++ks) {
        bhalf8 a[2], b[4];
        #pragma unroll
        for (int m = 0; m < 2; ++m)
            a[m] = *(const bhalf8*)(&m_lds[(wr * 32 + m * 16 + lr) * ESTRIDE + ks * 32 + lk * 8]);
        #pragma unroll
        for (int n = 0; n < 4; ++n)
            b[n] = *(const bhalf8*)(W4T + (size_t)(wc * 64 + n * 16 + lr) * H + ks * 32 + lk * 8);
        #pragma unroll
        for (int m = 0; m < 2; ++m)
            #pragma unroll
            for (int n = 0; n < 4; ++n)
                acc2[m][n] = __builtin_amdgcn_mfma_f32_16x16x32_bf16(a[m], b[n], acc2[m][n], 0, 0, 0);
    }

    float bn4[4];
    #pragma unroll
    for (int n = 0; n < 4; ++n) bn4[n] = b4[wc * 64 + n * 16 + lr];

    #pragma unroll
    for (int m = 0; m < 2; ++m)
        #pragma unroll
        for (int n = 0; n < 4; ++n)
            #pragma unroll
            for (int j = 0; j < 4; ++j) {
                int row = wr * 32 + m * 16 + lk * 4 + j;
                int col = wc * 64 + n * 16 + lr;
                int node = nb + row;
                if (node < NN) {
                    float base = nf[(size_t)node * H + col];
                    out0[(size_t)node * H + col] = base + silu_f(acc2[m][n][j] + bn4[n]);
                }
            }
}

extern "C" void kernel_launch(void* const* d_in, const int* in_sizes, int n_in,
                              void* d_out, int out_size, void* d_ws, size_t ws_size,
                              hipStream_t stream) {
    const float* nf  = (const float*)d_in[0];
    const float* lat = (const float*)d_in[2];
    const float* fd  = (const float*)d_in[3];
    const float* W1  = (const float*)d_in[4];
    const float* b1  = (const float*)d_in[5];
    const float* W2  = (const float*)d_in[6];
    const float* b2  = (const float*)d_in[7];
    const float* W3  = (const float*)d_in[8];
    const float* b3  = (const float*)d_in[9];
    const float* W4  = (const float*)d_in[10];
    const float* b4  = (const float*)d_in[11];
    const int* ei    = (const int*)d_in[12];
    const int* e2g   = (const int*)d_in[13];

    float* out0     = (float*)d_out;
    float* out_edge = (float*)d_out + (size_t)NN * H;

    char* ws = (char*)d_ws;
    size_t off = 0;
    float* agg = (float*)(ws + off);                    off += (size_t)NN * H * 4;     // 25.6 MB
    // P12 [N,256] bf16 aliases agg: P12 dead before agg_kernel writes agg
    unsigned short* P12 = (unsigned short*)agg;
    int* cnt_i      = (int*)(ws + off);                 off += (size_t)NB * 256 * 4;
    int* fill       = (int*)(ws + off);                 off += (size_t)NB * 256 * 4;
    int* row_start  = (int*)(ws + off);                 off += (size_t)NB * 256 * 4;
    int* bsum       = (int*)(ws + off);                 off += 256 * 4;
    int* bbase      = (int*)(ws + off);                 off += 256 * 4;
    int* eidx       = (int*)(ws + off);                 off += (size_t)EE * 4;         // 3.2 MB
    unsigned short* W12T = (unsigned short*)(ws + off); off += (size_t)256 * H * 2;    // 64 KB
    unsigned short* W2T  = (unsigned short*)(ws + off); off += (size_t)H * H * 2;
    unsigned short* W3T  = (unsigned short*)(ws + off); off += (size_t)H * K3 * 2;
    unsigned short* W4T  = (unsigned short*)(ws + off); off += (size_t)H * H * 2;
    unsigned short* Qb   = (unsigned short*)(ws + off); off += (size_t)GG * H * 2;     // 64 KB
    const float* W1fd = W1 + (size_t)265 * H;   // fd rows of W1, used in-place

    // zero cnt_i + fill (adjacent)
    (void)hipMemsetAsync(cnt_i, 0, (size_t)NB * 256 * 4 * 2, stream);

    transpose_w_kernel<<<dim3(1, H), 256, 0, stream>>>(W2, W2T, H, H);
    transpose_w_kernel<<<dim3(1, H), 256, 0, stream>>>(W3, W3T, K3, K3);
    transpose_w_kernel<<<dim3(1, H), 256, 0, stream>>>(W4, W4T, H, H);
    w12t_kernel<<<256, 128, 0, stream>>>(W1, W12T);
    q_kernel<<<GG, 128, 0, stream>>>(lat, W1, b1, Qb);
    p12_kernel<<<(NN + 63) / 64, 256, 0, stream>>>(nf, W12T, P12);

    // CSR build
    count_kernel<<<(EE + 255) / 256, 256, 0, stream>>>(ei, cnt_i);
    scan1_kernel<<<NB, 256, 0, stream>>>(cnt_i, bsum);
    scan2_kernel<<<1, 256, 0, stream>>>(bsum, bbase);
    scan3_kernel<<<NB, 256, 0, stream>>>(cnt_i, bbase, row_start);
    scatter_kernel<<<(EE + 255) / 256, 256, 0, stream>>>(ei, row_start, fill, eidx);

    edge_kernel<<<EE / 128, 256, 0, stream>>>(P12, Qb, fd, W1fd, W2T, b2,
                                              ei, e2g, out_edge);
    agg_kernel<<<(NN + 3) / 4, 256, 0, stream>>>(out_edge, row_start, cnt_i, eidx, agg);
    node_kernel<<<(NN + 63) / 64, 256, 0, stream>>>(nf, agg, W3T, b3, W4T, b4, out0);
}

// Round 7
// 468.407 us; speedup vs baseline: 1.3094x; 1.0276x over previous
//
#include <hip/hip_runtime.h>
#include <hip/hip_bf16.h>
#include <math.h>

#define H  128
#define NN 50000
#define EE 800000
#define GG 256
#define NB 196          // ceil(NN/256)

#define K3 256
#define NSTRIDE 264     // node x-tile LDS row stride
#define ESTRIDE 136     // hidden tile LDS row stride
#define PSTRIDE 136     // p12 staging stride

typedef __attribute__((ext_vector_type(8))) short bhalf8;
typedef __attribute__((ext_vector_type(4))) float f32x4;

__device__ __forceinline__ float silu_f(float x) {
    return x / (1.0f + __expf(-x));
}

// fp32 -> bf16 round-to-nearest-even
__device__ __forceinline__ unsigned short f2bf(float x) {
    unsigned int u = __float_as_uint(x);
    unsigned int r = 0x7fffu + ((u >> 16) & 1u);
    return (unsigned short)((u + r) >> 16);
}

// bf16 bits -> fp32
__device__ __forceinline__ float bf2f(unsigned short s) {
    return __uint_as_float(((unsigned int)s) << 16);
}

// ---- prep kernels ----

// W [K][128] fp32 -> WT [128][Kpad] bf16
__global__ void transpose_w_kernel(const float* __restrict__ W, unsigned short* __restrict__ WT,
                                   int K, int Kpad) {
    int k = blockIdx.x * blockDim.x + threadIdx.x;
    int c = blockIdx.y;
    if (k >= Kpad) return;
    WT[(size_t)c * Kpad + k] = (k < K) ? f2bf(W[(size_t)k * H + c]) : (unsigned short)0;
}

// W12T[j][k]: j<128 -> W1[k][j] (P1 part), j>=128 -> W1[128+k][j-128] (P2 part)
__global__ void w12t_kernel(const float* __restrict__ W1, unsigned short* __restrict__ W12T) {
    int j = blockIdx.x, k = threadIdx.x;   // 256 blocks x 128 threads
    float v = (j < 128) ? W1[(size_t)k * H + j] : W1[(size_t)(128 + k) * H + (j - 128)];
    W12T[(size_t)j * H + k] = f2bf(v);
}

// Q[g][c] = b1[c] + sum_r lat_ips[g][r] * W1[256+r][c]   (bf16 out)
__global__ void q_kernel(const float* __restrict__ lat, const float* __restrict__ W1,
                         const float* __restrict__ b1, unsigned short* __restrict__ Qb) {
    int g = blockIdx.x, c = threadIdx.x;   // 256 x 128
    const float* L = lat + g * 9;
    float q = b1[c];
    #pragma unroll
    for (int i = 0; i < 3; ++i)
        #pragma unroll
        for (int k = 0; k < 3; ++k) {
            float ip = L[i*3+0]*L[k*3+0] + L[i*3+1]*L[k*3+1] + L[i*3+2]*L[k*3+2];
            q += ip * W1[(size_t)(256 + i * 3 + k) * H + c];
        }
    Qb[(size_t)g * H + c] = f2bf(q);
}

// P12[n][0:128] = nf[n] @ W1a ; P12[n][128:256] = nf[n] @ W1b  (bf16 out)
__global__ __launch_bounds__(256) void p12_kernel(
    const float* __restrict__ nf, const unsigned short* __restrict__ W12T,
    unsigned short* __restrict__ P12)
{
    __shared__ unsigned short x_lds[64 * PSTRIDE];
    int tid = threadIdx.x;
    int nb = blockIdx.x * 64;

    #pragma unroll
    for (int p = 0; p < 8; ++p) {
        int idx = p * 256 + tid;
        int n = idx >> 5, c = idx & 31;
        int node = nb + n; if (node >= NN) node = NN - 1;
        float4 v = *(const float4*)(nf + (size_t)node * H + c * 4);
        ushort4 o;
        o.x = f2bf(v.x); o.y = f2bf(v.y); o.z = f2bf(v.z); o.w = f2bf(v.w);
        *(ushort4*)(&x_lds[n * PSTRIDE + c * 4]) = o;
    }
    __syncthreads();

    int wid = tid >> 6, lane = tid & 63;
    int wr = wid & 1, wc = wid >> 1;       // rows wr*32.., cols wc*128..
    int lr = lane & 15, lk = lane >> 4;

    f32x4 acc[2][8];
    #pragma unroll
    for (int m = 0; m < 2; ++m)
        #pragma unroll
        for (int n = 0; n < 8; ++n) acc[m][n] = (f32x4){0.f, 0.f, 0.f, 0.f};

    #pragma unroll
    for (int ks = 0; ks < 4; ++ks) {
        bhalf8 a[2], b[8];
        #pragma unroll
        for (int m = 0; m < 2; ++m)
            a[m] = *(const bhalf8*)(&x_lds[(wr * 32 + m * 16 + lr) * PSTRIDE + ks * 32 + lk * 8]);
        #pragma unroll
        for (int n = 0; n < 8; ++n)
            b[n] = *(const bhalf8*)(W12T + (size_t)(wc * 128 + n * 16 + lr) * H + ks * 32 + lk * 8);
        #pragma unroll
        for (int m = 0; m < 2; ++m)
            #pragma unroll
            for (int n = 0; n < 8; ++n)
                acc[m][n] = __builtin_amdgcn_mfma_f32_16x16x32_bf16(a[m], b[n], acc[m][n], 0, 0, 0);
    }

    #pragma unroll
    for (int m = 0; m < 2; ++m)
        #pragma unroll
        for (int n = 0; n < 8; ++n)
            #pragma unroll
            for (int j = 0; j < 4; ++j) {
                int row = wr * 32 + m * 16 + lk * 4 + j;
                int col = wc * 128 + n * 16 + lr;
                int node = nb + row;
                if (node < NN) P12[(size_t)node * 256 + col] = f2bf(acc[m][n][j]);
            }
}

// ---- CSR build ----

__global__ void count_kernel(const int* __restrict__ ei, int* __restrict__ cnt_i) {
    int e = blockIdx.x * blockDim.x + threadIdx.x;
    if (e < EE) atomicAdd(&cnt_i[ei[EE + e]], 1);
}

__global__ void scan1_kernel(const int* __restrict__ cnt_i, int* __restrict__ bsum) {
    __shared__ int red[256];
    int b = blockIdx.x, t = threadIdx.x;
    int n = b * 256 + t;
    red[t] = (n < NN) ? cnt_i[n] : 0;
    __syncthreads();
    for (int s = 128; s > 0; s >>= 1) {
        if (t < s) red[t] += red[t + s];
        __syncthreads();
    }
    if (t == 0) bsum[b] = red[0];
}

__global__ void scan2_kernel(const int* __restrict__ bsum, int* __restrict__ bbase) {
    __shared__ int tmp[256];
    int t = threadIdx.x;
    int c = (t < NB) ? bsum[t] : 0;
    tmp[t] = c;
    __syncthreads();
    for (int s = 1; s < 256; s <<= 1) {
        int u = (t >= s) ? tmp[t - s] : 0;
        __syncthreads();
        tmp[t] += u;
        __syncthreads();
    }
    if (t < NB) bbase[t] = tmp[t] - c;   // exclusive
}

__global__ void scan3_kernel(const int* __restrict__ cnt_i, const int* __restrict__ bbase,
                             int* __restrict__ row_start) {
    __shared__ int tmp[256];
    int b = blockIdx.x, t = threadIdx.x;
    int n = b * 256 + t;
    int c = (n < NN) ? cnt_i[n] : 0;
    tmp[t] = c;
    __syncthreads();
    for (int s = 1; s < 256; s <<= 1) {
        int u = (t >= s) ? tmp[t - s] : 0;
        __syncthreads();
        tmp[t] += u;
        __syncthreads();
    }
    if (n < NN) row_start[n] = bbase[b] + tmp[t] - c;   // exclusive
}

__global__ void scatter_kernel(const int* __restrict__ ei, const int* __restrict__ row_start,
                               int* __restrict__ fill, int* __restrict__ eidx) {
    int e = blockIdx.x * blockDim.x + threadIdx.x;
    if (e < EE) {
        int d = ei[EE + e];
        int pos = row_start[d] + atomicAdd(&fill[d], 1);
        eidx[pos] = e;
    }
}

// ---- edge kernel v4: CSR-ordered, fused segment-reduce into sums ----
// 128 CSR positions/block, 256 threads, 4 waves. mm2 swapped-operand:
//   mfma(W2_frag(A, col via lr), e1_frag(B, row via lr)) -> D[col=lk*4+j][row=lr]
__global__ __launch_bounds__(256) void edge_kernel(
    const unsigned short* __restrict__ P12, const unsigned short* __restrict__ Qb,
    const float* __restrict__ fdg, const float* __restrict__ W1fd,
    const unsigned short* __restrict__ W2T, const float* __restrict__ b2,
    const int* __restrict__ ei, const int* __restrict__ e2g,
    const int* __restrict__ eidx,
    float* __restrict__ out_edge, float* __restrict__ sums)
{
    __shared__ unsigned short e1[128 * ESTRIDE];   // 34.8 KB; reused as out-tile (bf16)
    __shared__ int sE[128], sSrc[128], sDst[128], sG[128];
    __shared__ float sFd[128 * 3];

    int tid = threadIdx.x;
    int eb = blockIdx.x * 128;

    if (tid < 128) sE[tid] = eidx[eb + tid];
    __syncthreads();
    if (tid < 128) {
        int e = sE[tid];
        sSrc[tid] = ei[e];
        sG[tid]   = e2g[e];
        sFd[tid * 3 + 0] = fdg[(size_t)e * 3 + 0];
        sFd[tid * 3 + 1] = fdg[(size_t)e * 3 + 1];
        sFd[tid * 3 + 2] = fdg[(size_t)e * 3 + 2];
    } else {
        sDst[tid - 128] = ei[EE + sE[tid - 128]];
    }
    __syncthreads();

    int c = tid & 15;
    // per-lane W1_fd columns (3 rows x 8 cols), L1-cached
    float4 wf[3][2];
    #pragma unroll
    for (int k = 0; k < 3; ++k)
        #pragma unroll
        for (int h = 0; h < 2; ++h)
            wf[k][h] = *(const float4*)(W1fd + k * H + c * 8 + h * 4);

    // ---- build e1[128][128] (bf16) ----
    #pragma unroll
    for (int p = 0; p < 8; ++p) {
        int r = p * 16 + (tid >> 4);
        int src = sSrc[r], dst = sDst[r], g = sG[r];
        bhalf8 p1 = *(const bhalf8*)(P12 + (size_t)src * 256 + c * 8);
        bhalf8 p2 = *(const bhalf8*)(P12 + (size_t)dst * 256 + 128 + c * 8);
        bhalf8 qv = *(const bhalf8*)(Qb + (size_t)g * H + c * 8);
        float f0 = sFd[r * 3 + 0], f1 = sFd[r * 3 + 1], f2v = sFd[r * 3 + 2];
        unsigned int w[4];
        #pragma unroll
        for (int jj = 0; jj < 4; ++jj) {
            unsigned int lo = 0, hi = 0;
            #pragma unroll
            for (int half = 0; half < 2; ++half) {
                int j = jj * 2 + half;
                const float* wfp = (const float*)&wf[0][0];
                float wv0 = wfp[j];
                float wv1 = wfp[8 + j];
                float wv2 = wfp[16 + j];
                float v = bf2f((unsigned short)p1[j]) + bf2f((unsigned short)p2[j])
                        + bf2f((unsigned short)qv[j])
                        + f0 * wv0 + f1 * wv1 + f2v * wv2;
                unsigned int us = f2bf(silu_f(v));
                if (half == 0) lo = us; else hi = us;
            }
            w[jj] = lo | (hi << 16);
        }
        uint4 pk; pk.x = w[0]; pk.y = w[1]; pk.z = w[2]; pk.w = w[3];
        *(uint4*)(&e1[r * ESTRIDE + c * 8]) = pk;
    }
    __syncthreads();

    // ---- mm2: D2[col][row] = W2T(A) x e1(B), 4 k-steps ----
    int wid = tid >> 6, lane = tid & 63;
    int wr = wid >> 1, wc = wid & 1;   // rows wr*64.., cols wc*64..
    int lr = lane & 15, lk = lane >> 4;

    f32x4 acc2[4][4];
    #pragma unroll
    for (int a = 0; a < 4; ++a)
        #pragma unroll
        for (int b = 0; b < 4; ++b) acc2[a][b] = (f32x4){0.f, 0.f, 0.f, 0.f};

    #pragma unroll
    for (int ks = 0; ks < 4; ++ks) {
        bhalf8 wa[4], xb[4];
        #pragma unroll
        for (int ai = 0; ai < 4; ++ai)
            wa[ai] = *(const bhalf8*)(W2T + (size_t)(wc * 64 + ai * 16 + lr) * H + ks * 32 + lk * 8);
        #pragma unroll
        for (int bj = 0; bj < 4; ++bj)
            xb[bj] = *(const bhalf8*)(&e1[(wr * 64 + bj * 16 + lr) * ESTRIDE + ks * 32 + lk * 8]);
        #pragma unroll
        for (int ai = 0; ai < 4; ++ai)
            #pragma unroll
            for (int bj = 0; bj < 4; ++bj)
                acc2[ai][bj] = __builtin_amdgcn_mfma_f32_16x16x32_bf16(wa[ai], xb[bj], acc2[ai][bj], 0, 0, 0);
    }

    float4 b2v[4];
    #pragma unroll
    for (int ai = 0; ai < 4; ++ai)
        b2v[ai] = *(const float4*)(b2 + wc * 64 + ai * 16 + lk * 4);

    __syncthreads();   // all mm2 reads of e1 done; safe to overwrite with out-tile

    // ---- epilogue: scatter fp32 rows to out_edge + bf16 out-tile to LDS ----
    #pragma unroll
    for (int ai = 0; ai < 4; ++ai)
        #pragma unroll
        for (int bj = 0; bj < 4; ++bj) {
            int rloc = wr * 64 + bj * 16 + lr;
            int colb = wc * 64 + ai * 16 + lk * 4;
            float4 o;
            o.x = silu_f(acc2[ai][bj][0] + b2v[ai].x);
            o.y = silu_f(acc2[ai][bj][1] + b2v[ai].y);
            o.z = silu_f(acc2[ai][bj][2] + b2v[ai].z);
            o.w = silu_f(acc2[ai][bj][3] + b2v[ai].w);
            *(float4*)(&out_edge[(size_t)sE[rloc] * H + colb]) = o;
            ushort4 pk;
            pk.x = f2bf(o.x); pk.y = f2bf(o.y); pk.z = f2bf(o.z); pk.w = f2bf(o.w);
            *(ushort4*)(&e1[rloc * ESTRIDE + colb]) = pk;
        }
    __syncthreads();

    // ---- segmented reduction over dst runs -> sums ----
    {
        int cc = tid & 127;
        int r0 = (tid >> 7) * 64;
        float acc = 0.0f;
        int curn = sDst[r0];
        for (int r = r0; r < r0 + 64; ++r) {
            int n = sDst[r];
            if (n != curn) {
                atomicAdd(&sums[(size_t)curn * H + cc], acc);
                acc = 0.0f;
                curn = n;
            }
            acc += bf2f(e1[r * ESTRIDE + cc]);
        }
        atomicAdd(&sums[(size_t)curn * H + cc], acc);
    }
}

// ---- node kernel: agg = sums/deg computed during staging ----
__global__ __launch_bounds__(256) void node_kernel(
    const float* __restrict__ nf, const float* __restrict__ sums,
    const int* __restrict__ cnt_i,
    const unsigned short* __restrict__ W3T, const float* __restrict__ b3,
    const unsigned short* __restrict__ W4T, const float* __restrict__ b4,
    float* __restrict__ out0)
{
    __shared__ unsigned short x_lds[64 * NSTRIDE];
    int tid = threadIdx.x;
    int nb = blockIdx.x * 64;

    // cols 0..127: nf (fp32 -> bf16)
    #pragma unroll
    for (int p = 0; p < 8; ++p) {
        int idx = p * 256 + tid;
        int n = idx >> 5, c = idx & 31;
        int node = nb + n; if (node >= NN) node = NN - 1;
        float4 v = *(const float4*)(nf + (size_t)node * H + c * 4);
        ushort4 o;
        o.x = f2bf(v.x); o.y = f2bf(v.y); o.z = f2bf(v.z); o.w = f2bf(v.w);
        *(ushort4*)(&x_lds[n * NSTRIDE + c * 4]) = o;
    }
    // cols 128..255: agg = sums/max(deg,1)
    #pragma unroll
    for (int p = 0; p < 8; ++p) {
        int idx = p * 256 + tid;
        int n = idx >> 5, c = idx & 31;
        int node = nb + n; if (node >= NN) node = NN - 1;
        float4 s = *(const float4*)(sums + (size_t)node * H + c * 4);
        float inv = 1.0f / fmaxf((float)cnt_i[node], 1.0f);
        ushort4 o;
        o.x = f2bf(s.x * inv); o.y = f2bf(s.y * inv);
        o.z = f2bf(s.z * inv); o.w = f2bf(s.w * inv);
        *(ushort4*)(&x_lds[n * NSTRIDE + 128 + c * 4]) = o;
    }
    __syncthreads();

    int wid = tid >> 6, lane = tid & 63;
    int wr = wid >> 1, wc = wid & 1;
    int lr = lane & 15, lk = lane >> 4;

    f32x4 acc[2][4];
    #pragma unroll
    for (int m = 0; m < 2; ++m)
        #pragma unroll
        for (int n = 0; n < 4; ++n) acc[m][n] = (f32x4){0.f, 0.f, 0.f, 0.f};

    #pragma unroll
    for (int ks = 0; ks < 8; ++ks) {
        bhalf8 a[2], b[4];
        #pragma unroll
        for (int m = 0; m < 2; ++m)
            a[m] = *(const bhalf8*)(&x_lds[(wr * 32 + m * 16 + lr) * NSTRIDE + ks * 32 + lk * 8]);
        #pragma unroll
        for (int n = 0; n < 4; ++n)
            b[n] = *(const bhalf8*)(W3T + (size_t)(wc * 64 + n * 16 + lr) * K3 + ks * 32 + lk * 8);
        #pragma unroll
        for (int m = 0; m < 2; ++m)
            #pragma unroll
            for (int n = 0; n < 4; ++n)
                acc[m][n] = __builtin_amdgcn_mfma_f32_16x16x32_bf16(a[m], b[n], acc[m][n], 0, 0, 0);
    }

    float bn3[4];
    #pragma unroll
    for (int n = 0; n < 4; ++n) bn3[n] = b3[wc * 64 + n * 16 + lr];

    __syncthreads();
    unsigned short* m_lds = x_lds;
    #pragma unroll
    for (int m = 0; m < 2; ++m)
        #pragma unroll
        for (int n = 0; n < 4; ++n)
            #pragma unroll
            for (int j = 0; j < 4; ++j) {
                int row = wr * 32 + m * 16 + lk * 4 + j;
                int col = wc * 64 + n * 16 + lr;
                m_lds[row * ESTRIDE + col] = f2bf(silu_f(acc[m][n][j] + bn3[n]));
            }
    __syncthreads();

    f32x4 acc2[2][4];
    #pragma unroll
    for (int m = 0; m < 2; ++m)
        #pragma unroll
        for (int n = 0; n < 4; ++n) acc2[m][n] = (f32x4){0.f, 0.f, 0.f, 0.f};

    #pragma unroll
    for (int ks = 0; ks < 4; ++ks) {
        bhalf8 a[2], b[4];
        #pragma unroll
        for (int m = 0; m < 2; ++m)
            a[m] = *(const bhalf8*)(&m_lds[(wr * 32 + m * 16 + lr) * ESTRIDE + ks * 32 + lk * 8]);
        #pragma unroll
        for (int n = 0; n < 4; ++n)
            b[n] = *(const bhalf8*)(W4T + (size_t)(wc * 64 + n * 16 + lr) * H + ks * 32 + lk * 8);
        #pragma unroll
        for (int m = 0; m < 2; ++m)
            #pragma unroll
            for (int n = 0; n < 4; ++n)
                acc2[m][n] = __builtin_amdgcn_mfma_f32_16x16x32_bf16(a[m], b[n], acc2[m][n], 0, 0, 0);
    }

    float bn4[4];
    #pragma unroll
    for (int n = 0; n < 4; ++n) bn4[n] = b4[wc * 64 + n * 16 + lr];

    #pragma unroll
    for (int m = 0; m < 2; ++m)
        #pragma unroll
        for (int n = 0; n < 4; ++n)
            #pragma unroll
            for (int j = 0; j < 4; ++j) {
                int row = wr * 32 + m * 16 + lk * 4 + j;
                int col = wc * 64 + n * 16 + lr;
                int node = nb + row;
                if (node < NN) {
                    float base = nf[(size_t)node * H + col];
                    out0[(size_t)node * H + col] = base + silu_f(acc2[m][n][j] + bn4[n]);
                }
            }
}

extern "C" void kernel_launch(void* const* d_in, const int* in_sizes, int n_in,
                              void* d_out, int out_size, void* d_ws, size_t ws_size,
                              hipStream_t stream) {
    const float* nf  = (const float*)d_in[0];
    const float* lat = (const float*)d_in[2];
    const float* fd  = (const float*)d_in[3];
    const float* W1  = (const float*)d_in[4];
    const float* b1  = (const float*)d_in[5];
    const float* W2  = (const float*)d_in[6];
    const float* b2  = (const float*)d_in[7];
    const float* W3  = (const float*)d_in[8];
    const float* b3  = (const float*)d_in[9];
    const float* W4  = (const float*)d_in[10];
    const float* b4  = (const float*)d_in[11];
    const int* ei    = (const int*)d_in[12];
    const int* e2g   = (const int*)d_in[13];

    float* out0     = (float*)d_out;
    float* out_edge = (float*)d_out + (size_t)NN * H;

    char* ws = (char*)d_ws;
    size_t off = 0;
    float* sums = (float*)(ws + off);                   off += (size_t)NN * H * 4;     // 25.6 MB (memset)
    int* cnt_i      = (int*)(ws + off);                 off += (size_t)NB * 256 * 4;   // (memset)
    int* fill       = (int*)(ws + off);                 off += (size_t)NB * 256 * 4;   // (memset)
    int* row_start  = (int*)(ws + off);                 off += (size_t)NB * 256 * 4;
    int* bsum       = (int*)(ws + off);                 off += 256 * 4;
    int* bbase      = (int*)(ws + off);                 off += 256 * 4;
    int* eidx       = (int*)(ws + off);                 off += (size_t)EE * 4;         // 3.2 MB
    unsigned short* P12  = (unsigned short*)(ws + off); off += (size_t)NN * 256 * 2;   // 25.6 MB
    unsigned short* W12T = (unsigned short*)(ws + off); off += (size_t)256 * H * 2;    // 64 KB
    unsigned short* W2T  = (unsigned short*)(ws + off); off += (size_t)H * H * 2;
    unsigned short* W3T  = (unsigned short*)(ws + off); off += (size_t)H * K3 * 2;
    unsigned short* W4T  = (unsigned short*)(ws + off); off += (size_t)H * H * 2;
    unsigned short* Qb   = (unsigned short*)(ws + off); off += (size_t)GG * H * 2;     // 64 KB
    const float* W1fd = W1 + (size_t)265 * H;   // fd rows of W1, used in-place

    // zero sums + cnt_i + fill (adjacent)
    (void)hipMemsetAsync(sums, 0, (size_t)NN * H * 4 + (size_t)NB * 256 * 4 * 2, stream);

    transpose_w_kernel<<<dim3(1, H), 256, 0, stream>>>(W2, W2T, H, H);
    transpose_w_kernel<<<dim3(1, H), 256, 0, stream>>>(W3, W3T, K3, K3);
    transpose_w_kernel<<<dim3(1, H), 256, 0, stream>>>(W4, W4T, H, H);
    w12t_kernel<<<256, 128, 0, stream>>>(W1, W12T);
    q_kernel<<<GG, 128, 0, stream>>>(lat, W1, b1, Qb);
    p12_kernel<<<(NN + 63) / 64, 256, 0, stream>>>(nf, W12T, P12);

    // CSR build
    count_kernel<<<(EE + 255) / 256, 256, 0, stream>>>(ei, cnt_i);
    scan1_kernel<<<NB, 256, 0, stream>>>(cnt_i, bsum);
    scan2_kernel<<<1, 256, 0, stream>>>(bsum, bbase);
    scan3_kernel<<<NB, 256, 0, stream>>>(cnt_i, bbase, row_start);
    scatter_kernel<<<(EE + 255) / 256, 256, 0, stream>>>(ei, row_start, fill, eidx);

    edge_kernel<<<EE / 128, 256, 0, stream>>>(P12, Qb, fd, W1fd, W2T, b2,
                                              ei, e2g, eidx, out_edge, sums);
    node_kernel<<<(NN + 63) / 64, 256, 0, stream>>>(nf, sums, cnt_i, W3T, b3, W4T, b4, out0);
}

// Round 8
// 410.056 us; speedup vs baseline: 1.4957x; 1.1423x over previous
//
#include <hip/hip_runtime.h>
#include <hip/hip_bf16.h>
#include <math.h>

#define H  128
#define NN 50000
#define EE 800000
#define GG 256
#define NB 196          // ceil(NN/256)

#define K3 256
#define NSTRIDE 264     // node x-tile LDS row stride
#define ESTRIDE 136     // hidden tile LDS row stride
#define PSTRIDE 136     // p12 staging stride

typedef __attribute__((ext_vector_type(8))) short bhalf8;
typedef __attribute__((ext_vector_type(4))) float f32x4;

__device__ __forceinline__ float silu_f(float x) {
    return x / (1.0f + __expf(-x));
}

// fp32 -> bf16 round-to-nearest-even
__device__ __forceinline__ unsigned short f2bf(float x) {
    unsigned int u = __float_as_uint(x);
    unsigned int r = 0x7fffu + ((u >> 16) & 1u);
    return (unsigned short)((u + r) >> 16);
}

// bf16 bits -> fp32
__device__ __forceinline__ float bf2f(unsigned short s) {
    return __uint_as_float(((unsigned int)s) << 16);
}

// ---- prep kernels ----

// W [K][128] fp32 -> WT [128][Kpad] bf16
__global__ void transpose_w_kernel(const float* __restrict__ W, unsigned short* __restrict__ WT,
                                   int K, int Kpad) {
    int k = blockIdx.x * blockDim.x + threadIdx.x;
    int c = blockIdx.y;
    if (k >= Kpad) return;
    WT[(size_t)c * Kpad + k] = (k < K) ? f2bf(W[(size_t)k * H + c]) : (unsigned short)0;
}

// W12T[j][k]: j<128 -> W1[k][j] (P1 part), j>=128 -> W1[128+k][j-128] (P2 part)
__global__ void w12t_kernel(const float* __restrict__ W1, unsigned short* __restrict__ W12T) {
    int j = blockIdx.x, k = threadIdx.x;   // 256 blocks x 128 threads
    float v = (j < 128) ? W1[(size_t)k * H + j] : W1[(size_t)(128 + k) * H + (j - 128)];
    W12T[(size_t)j * H + k] = f2bf(v);
}

// Q[g][c] = b1[c] + sum_r lat_ips[g][r] * W1[256+r][c]   (bf16 out)
__global__ void q_kernel(const float* __restrict__ lat, const float* __restrict__ W1,
                         const float* __restrict__ b1, unsigned short* __restrict__ Qb) {
    int g = blockIdx.x, c = threadIdx.x;   // 256 x 128
    const float* L = lat + g * 9;
    float q = b1[c];
    #pragma unroll
    for (int i = 0; i < 3; ++i)
        #pragma unroll
        for (int k = 0; k < 3; ++k) {
            float ip = L[i*3+0]*L[k*3+0] + L[i*3+1]*L[k*3+1] + L[i*3+2]*L[k*3+2];
            q += ip * W1[(size_t)(256 + i * 3 + k) * H + c];
        }
    Qb[(size_t)g * H + c] = f2bf(q);
}

// P12[n][0:128] = nf[n] @ W1a ; P12[n][128:256] = nf[n] @ W1b  (bf16 out)
__global__ __launch_bounds__(256) void p12_kernel(
    const float* __restrict__ nf, const unsigned short* __restrict__ W12T,
    unsigned short* __restrict__ P12)
{
    __shared__ unsigned short x_lds[64 * PSTRIDE];
    int tid = threadIdx.x;
    int nb = blockIdx.x * 64;

    #pragma unroll
    for (int p = 0; p < 8; ++p) {
        int idx = p * 256 + tid;
        int n = idx >> 5, c = idx & 31;
        int node = nb + n; if (node >= NN) node = NN - 1;
        float4 v = *(const float4*)(nf + (size_t)node * H + c * 4);
        ushort4 o;
        o.x = f2bf(v.x); o.y = f2bf(v.y); o.z = f2bf(v.z); o.w = f2bf(v.w);
        *(ushort4*)(&x_lds[n * PSTRIDE + c * 4]) = o;
    }
    __syncthreads();

    int wid = tid >> 6, lane = tid & 63;
    int wr = wid & 1, wc = wid >> 1;       // rows wr*32.., cols wc*128..
    int lr = lane & 15, lk = lane >> 4;

    f32x4 acc[2][8];
    #pragma unroll
    for (int m = 0; m < 2; ++m)
        #pragma unroll
        for (int n = 0; n < 8; ++n) acc[m][n] = (f32x4){0.f, 0.f, 0.f, 0.f};

    #pragma unroll
    for (int ks = 0; ks < 4; ++ks) {
        bhalf8 a[2], b[8];
        #pragma unroll
        for (int m = 0; m < 2; ++m)
            a[m] = *(const bhalf8*)(&x_lds[(wr * 32 + m * 16 + lr) * PSTRIDE + ks * 32 + lk * 8]);
        #pragma unroll
        for (int n = 0; n < 8; ++n)
            b[n] = *(const bhalf8*)(W12T + (size_t)(wc * 128 + n * 16 + lr) * H + ks * 32 + lk * 8);
        #pragma unroll
        for (int m = 0; m < 2; ++m)
            #pragma unroll
            for (int n = 0; n < 8; ++n)
                acc[m][n] = __builtin_amdgcn_mfma_f32_16x16x32_bf16(a[m], b[n], acc[m][n], 0, 0, 0);
    }

    #pragma unroll
    for (int m = 0; m < 2; ++m)
        #pragma unroll
        for (int n = 0; n < 8; ++n)
            #pragma unroll
            for (int j = 0; j < 4; ++j) {
                int row = wr * 32 + m * 16 + lk * 4 + j;
                int col = wc * 128 + n * 16 + lr;
                int node = nb + row;
                if (node < NN) P12[(size_t)node * 256 + col] = f2bf(acc[m][n][j]);
            }
}

// ---- CSR build ----

__global__ void count_kernel(const int* __restrict__ ei, int* __restrict__ cnt_i) {
    int e = blockIdx.x * blockDim.x + threadIdx.x;
    if (e < EE) atomicAdd(&cnt_i[ei[EE + e]], 1);
}

__global__ void scan1_kernel(const int* __restrict__ cnt_i, int* __restrict__ bsum) {
    __shared__ int red[256];
    int b = blockIdx.x, t = threadIdx.x;
    int n = b * 256 + t;
    red[t] = (n < NN) ? cnt_i[n] : 0;
    __syncthreads();
    for (int s = 128; s > 0; s >>= 1) {
        if (t < s) red[t] += red[t + s];
        __syncthreads();
    }
    if (t == 0) bsum[b] = red[0];
}

__global__ void scan2_kernel(const int* __restrict__ bsum, int* __restrict__ bbase) {
    __shared__ int tmp[256];
    int t = threadIdx.x;
    int c = (t < NB) ? bsum[t] : 0;
    tmp[t] = c;
    __syncthreads();
    for (int s = 1; s < 256; s <<= 1) {
        int u = (t >= s) ? tmp[t - s] : 0;
        __syncthreads();
        tmp[t] += u;
        __syncthreads();
    }
    if (t < NB) bbase[t] = tmp[t] - c;   // exclusive
}

__global__ void scan3_kernel(const int* __restrict__ cnt_i, const int* __restrict__ bbase,
                             int* __restrict__ row_start) {
    __shared__ int tmp[256];
    int b = blockIdx.x, t = threadIdx.x;
    int n = b * 256 + t;
    int c = (n < NN) ? cnt_i[n] : 0;
    tmp[t] = c;
    __syncthreads();
    for (int s = 1; s < 256; s <<= 1) {
        int u = (t >= s) ? tmp[t - s] : 0;
        __syncthreads();
        tmp[t] += u;
        __syncthreads();
    }
    if (n < NN) row_start[n] = bbase[b] + tmp[t] - c;   // exclusive
}

__global__ void scatter_kernel(const int* __restrict__ ei, const int* __restrict__ row_start,
                               int* __restrict__ fill, int* __restrict__ eidx) {
    int e = blockIdx.x * blockDim.x + threadIdx.x;
    if (e < EE) {
        int d = ei[EE + e];
        int pos = row_start[d] + atomicAdd(&fill[d], 1);
        eidx[pos] = e;
    }
}

// ---- edge kernel v5: CSR-ordered, fused segment-reduce, 512 threads ----
// 128 CSR positions/block, 8 waves. mm2 swapped-operand:
//   mfma(W2_frag(A, col via lr), e1_frag(B, row via lr)) -> D[col=lk*4+j][row=lr]
__global__ __launch_bounds__(512, 6) void edge_kernel(
    const unsigned short* __restrict__ P12, const unsigned short* __restrict__ Qb,
    const float* __restrict__ fdg, const float* __restrict__ W1fd,
    const unsigned short* __restrict__ W2T, const float* __restrict__ b2,
    const int* __restrict__ ei, const int* __restrict__ e2g,
    const int* __restrict__ eidx,
    float* __restrict__ out_edge, float* __restrict__ sums)
{
    __shared__ unsigned short e1[128 * ESTRIDE];   // 34.8 KB; reused as out-tile (bf16)
    __shared__ int sE[128], sSrc[128], sDst[128], sG[128];
    __shared__ float sFd[128 * 3];

    int tid = threadIdx.x;
    int eb = blockIdx.x * 128;

    if (tid < 128) sE[tid] = eidx[eb + tid];
    __syncthreads();
    if (tid < 128) {
        int e = sE[tid];
        sSrc[tid] = ei[e];
        sG[tid]   = e2g[e];
    } else if (tid < 256) {
        sDst[tid - 128] = ei[EE + sE[tid - 128]];
    } else if (tid < 384) {
        int r = tid - 256;
        int e = sE[r];
        sFd[r * 3 + 0] = fdg[(size_t)e * 3 + 0];
        sFd[r * 3 + 1] = fdg[(size_t)e * 3 + 1];
        sFd[r * 3 + 2] = fdg[(size_t)e * 3 + 2];
    }
    __syncthreads();

    int c = tid & 15;
    // per-lane W1_fd columns (3 rows x 8 cols), L1-cached
    float4 wf[3][2];
    #pragma unroll
    for (int k = 0; k < 3; ++k)
        #pragma unroll
        for (int h = 0; h < 2; ++h)
            wf[k][h] = *(const float4*)(W1fd + k * H + c * 8 + h * 4);

    // ---- build e1[128][128] (bf16): 4 rows per thread ----
    #pragma unroll
    for (int p = 0; p < 4; ++p) {
        int r = p * 32 + (tid >> 4);
        int src = sSrc[r], dst = sDst[r], g = sG[r];
        bhalf8 p1 = *(const bhalf8*)(P12 + (size_t)src * 256 + c * 8);
        bhalf8 p2 = *(const bhalf8*)(P12 + (size_t)dst * 256 + 128 + c * 8);
        bhalf8 qv = *(const bhalf8*)(Qb + (size_t)g * H + c * 8);
        float f0 = sFd[r * 3 + 0], f1 = sFd[r * 3 + 1], f2v = sFd[r * 3 + 2];
        unsigned int w[4];
        #pragma unroll
        for (int jj = 0; jj < 4; ++jj) {
            unsigned int lo = 0, hi = 0;
            #pragma unroll
            for (int half = 0; half < 2; ++half) {
                int j = jj * 2 + half;
                const float* wfp = (const float*)&wf[0][0];
                float wv0 = wfp[j];
                float wv1 = wfp[8 + j];
                float wv2 = wfp[16 + j];
                float v = bf2f((unsigned short)p1[j]) + bf2f((unsigned short)p2[j])
                        + bf2f((unsigned short)qv[j])
                        + f0 * wv0 + f1 * wv1 + f2v * wv2;
                unsigned int us = f2bf(silu_f(v));
                if (half == 0) lo = us; else hi = us;
            }
            w[jj] = lo | (hi << 16);
        }
        uint4 pk; pk.x = w[0]; pk.y = w[1]; pk.z = w[2]; pk.w = w[3];
        *(uint4*)(&e1[r * ESTRIDE + c * 8]) = pk;
    }
    __syncthreads();

    // ---- mm2: 8 waves, each 64 rows x 32 cols ----
    int wid = tid >> 6, lane = tid & 63;
    int wr = wid >> 2, wcc = wid & 3;   // rows wr*64.., cols wcc*32..
    int lr = lane & 15, lk = lane >> 4;

    f32x4 acc2[2][4];
    #pragma unroll
    for (int a = 0; a < 2; ++a)
        #pragma unroll
        for (int b = 0; b < 4; ++b) acc2[a][b] = (f32x4){0.f, 0.f, 0.f, 0.f};

    #pragma unroll
    for (int ks = 0; ks < 4; ++ks) {
        bhalf8 wa[2], xb[4];
        #pragma unroll
        for (int ai = 0; ai < 2; ++ai)
            wa[ai] = *(const bhalf8*)(W2T + (size_t)(wcc * 32 + ai * 16 + lr) * H + ks * 32 + lk * 8);
        #pragma unroll
        for (int bj = 0; bj < 4; ++bj)
            xb[bj] = *(const bhalf8*)(&e1[(wr * 64 + bj * 16 + lr) * ESTRIDE + ks * 32 + lk * 8]);
        #pragma unroll
        for (int ai = 0; ai < 2; ++ai)
            #pragma unroll
            for (int bj = 0; bj < 4; ++bj)
                acc2[ai][bj] = __builtin_amdgcn_mfma_f32_16x16x32_bf16(wa[ai], xb[bj], acc2[ai][bj], 0, 0, 0);
    }

    float4 b2v[2];
    #pragma unroll
    for (int ai = 0; ai < 2; ++ai)
        b2v[ai] = *(const float4*)(b2 + wcc * 32 + ai * 16 + lk * 4);

    __syncthreads();   // all mm2 reads of e1 done; safe to overwrite with out-tile

    // ---- epilogue: scatter fp32 rows to out_edge + bf16 out-tile to LDS ----
    #pragma unroll
    for (int ai = 0; ai < 2; ++ai)
        #pragma unroll
        for (int bj = 0; bj < 4; ++bj) {
            int rloc = wr * 64 + bj * 16 + lr;
            int colb = wcc * 32 + ai * 16 + lk * 4;
            float4 o;
            o.x = silu_f(acc2[ai][bj][0] + b2v[ai].x);
            o.y = silu_f(acc2[ai][bj][1] + b2v[ai].y);
            o.z = silu_f(acc2[ai][bj][2] + b2v[ai].z);
            o.w = silu_f(acc2[ai][bj][3] + b2v[ai].w);
            *(float4*)(&out_edge[(size_t)sE[rloc] * H + colb]) = o;
            ushort4 pk;
            pk.x = f2bf(o.x); pk.y = f2bf(o.y); pk.z = f2bf(o.z); pk.w = f2bf(o.w);
            *(ushort4*)(&e1[rloc * ESTRIDE + colb]) = pk;
        }
    __syncthreads();

    // ---- segmented reduction over dst runs -> sums (32 rows per thread) ----
    {
        int cc = tid & 127;
        int r0 = (tid >> 7) * 32;
        float acc = 0.0f;
        int curn = sDst[r0];
        for (int r = r0; r < r0 + 32; ++r) {
            int n = sDst[r];
            if (n != curn) {
                atomicAdd(&sums[(size_t)curn * H + cc], acc);
                acc = 0.0f;
                curn = n;
            }
            acc += bf2f(e1[r * ESTRIDE + cc]);
        }
        atomicAdd(&sums[(size_t)curn * H + cc], acc);
    }
}

// ---- node kernel: agg = sums/deg computed during staging ----
__global__ __launch_bounds__(256) void node_kernel(
    const float* __restrict__ nf, const float* __restrict__ sums,
    const int* __restrict__ cnt_i,
    const unsigned short* __restrict__ W3T, const float* __restrict__ b3,
    const unsigned short* __restrict__ W4T, const float* __restrict__ b4,
    float* __restrict__ out0)
{
    __shared__ unsigned short x_lds[64 * NSTRIDE];
    int tid = threadIdx.x;
    int nb = blockIdx.x * 64;

    // cols 0..127: nf (fp32 -> bf16)
    #pragma unroll
    for (int p = 0; p < 8; ++p) {
        int idx = p * 256 + tid;
        int n = idx >> 5, c = idx & 31;
        int node = nb + n; if (node >= NN) node = NN - 1;
        float4 v = *(const float4*)(nf + (size_t)node * H + c * 4);
        ushort4 o;
        o.x = f2bf(v.x); o.y = f2bf(v.y); o.z = f2bf(v.z); o.w = f2bf(v.w);
        *(ushort4*)(&x_lds[n * NSTRIDE + c * 4]) = o;
    }
    // cols 128..255: agg = sums/max(deg,1)
    #pragma unroll
    for (int p = 0; p < 8; ++p) {
        int idx = p * 256 + tid;
        int n = idx >> 5, c = idx & 31;
        int node = nb + n; if (node >= NN) node = NN - 1;
        float4 s = *(const float4*)(sums + (size_t)node * H + c * 4);
        float inv = 1.0f / fmaxf((float)cnt_i[node], 1.0f);
        ushort4 o;
        o.x = f2bf(s.x * inv); o.y = f2bf(s.y * inv);
        o.z = f2bf(s.z * inv); o.w = f2bf(s.w * inv);
        *(ushort4*)(&x_lds[n * NSTRIDE + 128 + c * 4]) = o;
    }
    __syncthreads();

    int wid = tid >> 6, lane = tid & 63;
    int wr = wid >> 1, wc = wid & 1;
    int lr = lane & 15, lk = lane >> 4;

    f32x4 acc[2][4];
    #pragma unroll
    for (int m = 0; m < 2; ++m)
        #pragma unroll
        for (int n = 0; n < 4; ++n) acc[m][n] = (f32x4){0.f, 0.f, 0.f, 0.f};

    #pragma unroll
    for (int ks = 0; ks < 8; ++ks) {
        bhalf8 a[2], b[4];
        #pragma unroll
        for (int m = 0; m < 2; ++m)
            a[m] = *(const bhalf8*)(&x_lds[(wr * 32 + m * 16 + lr) * NSTRIDE + ks * 32 + lk * 8]);
        #pragma unroll
        for (int n = 0; n < 4; ++n)
            b[n] = *(const bhalf8*)(W3T + (size_t)(wc * 64 + n * 16 + lr) * K3 + ks * 32 + lk * 8);
        #pragma unroll
        for (int m = 0; m < 2; ++m)
            #pragma unroll
            for (int n = 0; n < 4; ++n)
                acc[m][n] = __builtin_amdgcn_mfma_f32_16x16x32_bf16(a[m], b[n], acc[m][n], 0, 0, 0);
    }

    float bn3[4];
    #pragma unroll
    for (int n = 0; n < 4; ++n) bn3[n] = b3[wc * 64 + n * 16 + lr];

    __syncthreads();
    unsigned short* m_lds = x_lds;
    #pragma unroll
    for (int m = 0; m < 2; ++m)
        #pragma unroll
        for (int n = 0; n < 4; ++n)
            #pragma unroll
            for (int j = 0; j < 4; ++j) {
                int row = wr * 32 + m * 16 + lk * 4 + j;
                int col = wc * 64 + n * 16 + lr;
                m_lds[row * ESTRIDE + col] = f2bf(silu_f(acc[m][n][j] + bn3[n]));
            }
    __syncthreads();

    f32x4 acc2[2][4];
    #pragma unroll
    for (int m = 0; m < 2; ++m)
        #pragma unroll
        for (int n = 0; n < 4; ++n) acc2[m][n] = (f32x4){0.f, 0.f, 0.f, 0.f};

    #pragma unroll
    for (int ks = 0; ks < 4; ++ks) {
        bhalf8 a[2], b[4];
        #pragma unroll
        for (int m = 0; m < 2; ++m)
            a[m] = *(const bhalf8*)(&m_lds[(wr * 32 + m * 16 + lr) * ESTRIDE + ks * 32 + lk * 8]);
        #pragma unroll
        for (int n = 0; n < 4; ++n)
            b[n] = *(const bhalf8*)(W4T + (size_t)(wc * 64 + n * 16 + lr) * H + ks * 32 + lk * 8);
        #pragma unroll
        for (int m = 0; m < 2; ++m)
            #pragma unroll
            for (int n = 0; n < 4; ++n)
                acc2[m][n] = __builtin_amdgcn_mfma_f32_16x16x32_bf16(a[m], b[n], acc2[m][n], 0, 0, 0);
    }

    float bn4[4];
    #pragma unroll
    for (int n = 0; n < 4; ++n) bn4[n] = b4[wc * 64 + n * 16 + lr];

    #pragma unroll
    for (int m = 0; m < 2; ++m)
        #pragma unroll
        for (int n = 0; n < 4; ++n)
            #pragma unroll
            for (int j = 0; j < 4; ++j) {
                int row = wr * 32 + m * 16 + lk * 4 + j;
                int col = wc * 64 + n * 16 + lr;
                int node = nb + row;
                if (node < NN) {
                    float base = nf[(size_t)node * H + col];
                    out0[(size_t)node * H + col] = base + silu_f(acc2[m][n][j] + bn4[n]);
                }
            }
}

extern "C" void kernel_launch(void* const* d_in, const int* in_sizes, int n_in,
                              void* d_out, int out_size, void* d_ws, size_t ws_size,
                              hipStream_t stream) {
    const float* nf  = (const float*)d_in[0];
    const float* lat = (const float*)d_in[2];
    const float* fd  = (const float*)d_in[3];
    const float* W1  = (const float*)d_in[4];
    const float* b1  = (const float*)d_in[5];
    const float* W2  = (const float*)d_in[6];
    const float* b2  = (const float*)d_in[7];
    const float* W3  = (const float*)d_in[8];
    const float* b3  = (const float*)d_in[9];
    const float* W4  = (const float*)d_in[10];
    const float* b4  = (const float*)d_in[11];
    const int* ei    = (const int*)d_in[12];
    const int* e2g   = (const int*)d_in[13];

    float* out0     = (float*)d_out;
    float* out_edge = (float*)d_out + (size_t)NN * H;

    char* ws = (char*)d_ws;
    size_t off = 0;
    float* sums = (float*)(ws + off);                   off += (size_t)NN * H * 4;     // 25.6 MB (memset)
    int* cnt_i      = (int*)(ws + off);                 off += (size_t)NB * 256 * 4;   // (memset)
    int* fill       = (int*)(ws + off);                 off += (size_t)NB * 256 * 4;   // (memset)
    int* row_start  = (int*)(ws + off);                 off += (size_t)NB * 256 * 4;
    int* bsum       = (int*)(ws + off);                 off += 256 * 4;
    int* bbase      = (int*)(ws + off);                 off += 256 * 4;
    int* eidx       = (int*)(ws + off);                 off += (size_t)EE * 4;         // 3.2 MB
    unsigned short* P12  = (unsigned short*)(ws + off); off += (size_t)NN * 256 * 2;   // 25.6 MB
    unsigned short* W12T = (unsigned short*)(ws + off); off += (size_t)256 * H * 2;    // 64 KB
    unsigned short* W2T  = (unsigned short*)(ws + off); off += (size_t)H * H * 2;
    unsigned short* W3T  = (unsigned short*)(ws + off); off += (size_t)H * K3 * 2;
    unsigned short* W4T  = (unsigned short*)(ws + off); off += (size_t)H * H * 2;
    unsigned short* Qb   = (unsigned short*)(ws + off); off += (size_t)GG * H * 2;     // 64 KB
    const float* W1fd = W1 + (size_t)265 * H;   // fd rows of W1, used in-place

    // zero sums + cnt_i + fill (adjacent)
    (void)hipMemsetAsync(sums, 0, (size_t)NN * H * 4 + (size_t)NB * 256 * 4 * 2, stream);

    transpose_w_kernel<<<dim3(1, H), 256, 0, stream>>>(W2, W2T, H, H);
    transpose_w_kernel<<<dim3(1, H), 256, 0, stream>>>(W3, W3T, K3, K3);
    transpose_w_kernel<<<dim3(1, H), 256, 0, stream>>>(W4, W4T, H, H);
    w12t_kernel<<<256, 128, 0, stream>>>(W1, W12T);
    q_kernel<<<GG, 128, 0, stream>>>(lat, W1, b1, Qb);
    p12_kernel<<<(NN + 63) / 64, 256, 0, stream>>>(nf, W12T, P12);

    // CSR build
    count_kernel<<<(EE + 255) / 256, 256, 0, stream>>>(ei, cnt_i);
    scan1_kernel<<<NB, 256, 0, stream>>>(cnt_i, bsum);
    scan2_kernel<<<1, 256, 0, stream>>>(bsum, bbase);
    scan3_kernel<<<NB, 256, 0, stream>>>(cnt_i, bbase, row_start);
    scatter_kernel<<<(EE + 255) / 256, 256, 0, stream>>>(ei, row_start, fill, eidx);

    edge_kernel<<<EE / 128, 512, 0, stream>>>(P12, Qb, fd, W1fd, W2T, b2,
                                              ei, e2g, eidx, out_edge, sums);
    node_kernel<<<(NN + 63) / 64, 256, 0, stream>>>(nf, sums, cnt_i, W3T, b3, W4T, b4, out0);
}

// Round 9
// 405.463 us; speedup vs baseline: 1.5126x; 1.0113x over previous
//
#include <hip/hip_runtime.h>
#include <hip/hip_bf16.h>
#include <math.h>

#define H  128
#define NN 50000
#define EE 800000
#define GG 256
#define NB 196          // ceil(NN/256)

#define K3 256
#define NSTRIDE 264     // node x-tile LDS row stride
#define ESTRIDE 136     // hidden tile LDS row stride
#define PSTRIDE 136     // p12 staging stride

typedef __attribute__((ext_vector_type(8))) short bhalf8;
typedef __attribute__((ext_vector_type(4))) float f32x4;

__device__ __forceinline__ float silu_f(float x) {
    return x / (1.0f + __expf(-x));
}

// fp32 -> bf16 round-to-nearest-even
__device__ __forceinline__ unsigned short f2bf(float x) {
    unsigned int u = __float_as_uint(x);
    unsigned int r = 0x7fffu + ((u >> 16) & 1u);
    return (unsigned short)((u + r) >> 16);
}

// bf16 bits -> fp32
__device__ __forceinline__ float bf2f(unsigned short s) {
    return __uint_as_float(((unsigned int)s) << 16);
}

// ---- prep kernels ----

// W [K][128] fp32 -> WT [128][Kpad] bf16
__global__ void transpose_w_kernel(const float* __restrict__ W, unsigned short* __restrict__ WT,
                                   int K, int Kpad) {
    int k = blockIdx.x * blockDim.x + threadIdx.x;
    int c = blockIdx.y;
    if (k >= Kpad) return;
    WT[(size_t)c * Kpad + k] = (k < K) ? f2bf(W[(size_t)k * H + c]) : (unsigned short)0;
}

// W12T[j][k]: j<128 -> W1[k][j] (P1 part), j>=128 -> W1[128+k][j-128] (P2 part)
__global__ void w12t_kernel(const float* __restrict__ W1, unsigned short* __restrict__ W12T) {
    int j = blockIdx.x, k = threadIdx.x;   // 256 blocks x 128 threads
    float v = (j < 128) ? W1[(size_t)k * H + j] : W1[(size_t)(128 + k) * H + (j - 128)];
    W12T[(size_t)j * H + k] = f2bf(v);
}

// Q[g][c] = b1[c] + sum_r lat_ips[g][r] * W1[256+r][c]   (bf16 out)
__global__ void q_kernel(const float* __restrict__ lat, const float* __restrict__ W1,
                         const float* __restrict__ b1, unsigned short* __restrict__ Qb) {
    int g = blockIdx.x, c = threadIdx.x;   // 256 x 128
    const float* L = lat + g * 9;
    float q = b1[c];
    #pragma unroll
    for (int i = 0; i < 3; ++i)
        #pragma unroll
        for (int k = 0; k < 3; ++k) {
            float ip = L[i*3+0]*L[k*3+0] + L[i*3+1]*L[k*3+1] + L[i*3+2]*L[k*3+2];
            q += ip * W1[(size_t)(256 + i * 3 + k) * H + c];
        }
    Qb[(size_t)g * H + c] = f2bf(q);
}

// P12[n][0:128] = nf[n] @ W1a ; P12[n][128:256] = nf[n] @ W1b  (bf16 out)
__global__ __launch_bounds__(256) void p12_kernel(
    const float* __restrict__ nf, const unsigned short* __restrict__ W12T,
    unsigned short* __restrict__ P12)
{
    __shared__ unsigned short x_lds[64 * PSTRIDE];
    int tid = threadIdx.x;
    int nb = blockIdx.x * 64;

    #pragma unroll
    for (int p = 0; p < 8; ++p) {
        int idx = p * 256 + tid;
        int n = idx >> 5, c = idx & 31;
        int node = nb + n; if (node >= NN) node = NN - 1;
        float4 v = *(const float4*)(nf + (size_t)node * H + c * 4);
        ushort4 o;
        o.x = f2bf(v.x); o.y = f2bf(v.y); o.z = f2bf(v.z); o.w = f2bf(v.w);
        *(ushort4*)(&x_lds[n * PSTRIDE + c * 4]) = o;
    }
    __syncthreads();

    int wid = tid >> 6, lane = tid & 63;
    int wr = wid & 1, wc = wid >> 1;       // rows wr*32.., cols wc*128..
    int lr = lane & 15, lk = lane >> 4;

    f32x4 acc[2][8];
    #pragma unroll
    for (int m = 0; m < 2; ++m)
        #pragma unroll
        for (int n = 0; n < 8; ++n) acc[m][n] = (f32x4){0.f, 0.f, 0.f, 0.f};

    #pragma unroll
    for (int ks = 0; ks < 4; ++ks) {
        bhalf8 a[2], b[8];
        #pragma unroll
        for (int m = 0; m < 2; ++m)
            a[m] = *(const bhalf8*)(&x_lds[(wr * 32 + m * 16 + lr) * PSTRIDE + ks * 32 + lk * 8]);
        #pragma unroll
        for (int n = 0; n < 8; ++n)
            b[n] = *(const bhalf8*)(W12T + (size_t)(wc * 128 + n * 16 + lr) * H + ks * 32 + lk * 8);
        #pragma unroll
        for (int m = 0; m < 2; ++m)
            #pragma unroll
            for (int n = 0; n < 8; ++n)
                acc[m][n] = __builtin_amdgcn_mfma_f32_16x16x32_bf16(a[m], b[n], acc[m][n], 0, 0, 0);
    }

    #pragma unroll
    for (int m = 0; m < 2; ++m)
        #pragma unroll
        for (int n = 0; n < 8; ++n)
            #pragma unroll
            for (int j = 0; j < 4; ++j) {
                int row = wr * 32 + m * 16 + lk * 4 + j;
                int col = wc * 128 + n * 16 + lr;
                int node = nb + row;
                if (node < NN) P12[(size_t)node * 256 + col] = f2bf(acc[m][n][j]);
            }
}

// ---- CSR build ----

__global__ void count_kernel(const int* __restrict__ ei, int* __restrict__ cnt_i) {
    int e = blockIdx.x * blockDim.x + threadIdx.x;
    if (e < EE) atomicAdd(&cnt_i[ei[EE + e]], 1);
}

__global__ void scan1_kernel(const int* __restrict__ cnt_i, int* __restrict__ bsum) {
    __shared__ int red[256];
    int b = blockIdx.x, t = threadIdx.x;
    int n = b * 256 + t;
    red[t] = (n < NN) ? cnt_i[n] : 0;
    __syncthreads();
    for (int s = 128; s > 0; s >>= 1) {
        if (t < s) red[t] += red[t + s];
        __syncthreads();
    }
    if (t == 0) bsum[b] = red[0];
}

__global__ void scan2_kernel(const int* __restrict__ bsum, int* __restrict__ bbase) {
    __shared__ int tmp[256];
    int t = threadIdx.x;
    int c = (t < NB) ? bsum[t] : 0;
    tmp[t] = c;
    __syncthreads();
    for (int s = 1; s < 256; s <<= 1) {
        int u = (t >= s) ? tmp[t - s] : 0;
        __syncthreads();
        tmp[t] += u;
        __syncthreads();
    }
    if (t < NB) bbase[t] = tmp[t] - c;   // exclusive
}

__global__ void scan3_kernel(const int* __restrict__ cnt_i, const int* __restrict__ bbase,
                             int* __restrict__ row_start) {
    __shared__ int tmp[256];
    int b = blockIdx.x, t = threadIdx.x;
    int n = b * 256 + t;
    int c = (n < NN) ? cnt_i[n] : 0;
    tmp[t] = c;
    __syncthreads();
    for (int s = 1; s < 256; s <<= 1) {
        int u = (t >= s) ? tmp[t - s] : 0;
        __syncthreads();
        tmp[t] += u;
        __syncthreads();
    }
    if (n < NN) row_start[n] = bbase[b] + tmp[t] - c;   // exclusive
}

__global__ void scatter_kernel(const int* __restrict__ ei, const int* __restrict__ row_start,
                               int* __restrict__ fill, int* __restrict__ eidx) {
    int e = blockIdx.x * blockDim.x + threadIdx.x;
    if (e < EE) {
        int d = ei[EE + e];
        int pos = row_start[d] + atomicAdd(&fill[d], 1);
        eidx[pos] = e;
    }
}

// ---- edge kernel v6: CSR-ordered, fused segment-reduce, coalesced row writes ----
__global__ __launch_bounds__(512, 6) void edge_kernel(
    const unsigned short* __restrict__ P12, const unsigned short* __restrict__ Qb,
    const float* __restrict__ fdg, const float* __restrict__ W1fd,
    const unsigned short* __restrict__ W2T, const float* __restrict__ b2,
    const int* __restrict__ ei, const int* __restrict__ e2g,
    const int* __restrict__ eidx,
    float* __restrict__ out_edge, float* __restrict__ sums)
{
    __shared__ unsigned short e1[128 * ESTRIDE];   // 34.8 KB; reused as out-tile (bf16)
    __shared__ int sE[128], sSrc[128], sDst[128], sG[128];
    __shared__ float sFd[128 * 3];

    int tid = threadIdx.x;
    int eb = blockIdx.x * 128;

    if (tid < 128) sE[tid] = eidx[eb + tid];
    __syncthreads();
    if (tid < 128) {
        int e = sE[tid];
        sSrc[tid] = ei[e];
        sG[tid]   = e2g[e];
    } else if (tid < 256) {
        sDst[tid - 128] = ei[EE + sE[tid - 128]];
    } else if (tid < 384) {
        int r = tid - 256;
        int e = sE[r];
        sFd[r * 3 + 0] = fdg[(size_t)e * 3 + 0];
        sFd[r * 3 + 1] = fdg[(size_t)e * 3 + 1];
        sFd[r * 3 + 2] = fdg[(size_t)e * 3 + 2];
    }
    __syncthreads();

    int c = tid & 15;
    // per-lane W1_fd columns (3 rows x 8 cols), L1-cached
    float4 wf[3][2];
    #pragma unroll
    for (int k = 0; k < 3; ++k)
        #pragma unroll
        for (int h = 0; h < 2; ++h)
            wf[k][h] = *(const float4*)(W1fd + k * H + c * 8 + h * 4);

    // ---- build e1[128][128] (bf16): 4 rows per thread ----
    #pragma unroll
    for (int p = 0; p < 4; ++p) {
        int r = p * 32 + (tid >> 4);
        int src = sSrc[r], dst = sDst[r], g = sG[r];
        bhalf8 p1 = *(const bhalf8*)(P12 + (size_t)src * 256 + c * 8);
        bhalf8 p2 = *(const bhalf8*)(P12 + (size_t)dst * 256 + 128 + c * 8);
        bhalf8 qv = *(const bhalf8*)(Qb + (size_t)g * H + c * 8);
        float f0 = sFd[r * 3 + 0], f1 = sFd[r * 3 + 1], f2v = sFd[r * 3 + 2];
        unsigned int w[4];
        #pragma unroll
        for (int jj = 0; jj < 4; ++jj) {
            unsigned int lo = 0, hi = 0;
            #pragma unroll
            for (int half = 0; half < 2; ++half) {
                int j = jj * 2 + half;
                const float* wfp = (const float*)&wf[0][0];
                float wv0 = wfp[j];
                float wv1 = wfp[8 + j];
                float wv2 = wfp[16 + j];
                float v = bf2f((unsigned short)p1[j]) + bf2f((unsigned short)p2[j])
                        + bf2f((unsigned short)qv[j])
                        + f0 * wv0 + f1 * wv1 + f2v * wv2;
                unsigned int us = f2bf(silu_f(v));
                if (half == 0) lo = us; else hi = us;
            }
            w[jj] = lo | (hi << 16);
        }
        uint4 pk; pk.x = w[0]; pk.y = w[1]; pk.z = w[2]; pk.w = w[3];
        *(uint4*)(&e1[r * ESTRIDE + c * 8]) = pk;
    }
    __syncthreads();

    // ---- mm2: 8 waves, each 64 rows x 32 cols ----
    int wid = tid >> 6, lane = tid & 63;
    int wr = wid >> 2, wcc = wid & 3;   // rows wr*64.., cols wcc*32..
    int lr = lane & 15, lk = lane >> 4;

    f32x4 acc2[2][4];
    #pragma unroll
    for (int a = 0; a < 2; ++a)
        #pragma unroll
        for (int b = 0; b < 4; ++b) acc2[a][b] = (f32x4){0.f, 0.f, 0.f, 0.f};

    #pragma unroll
    for (int ks = 0; ks < 4; ++ks) {
        bhalf8 wa[2], xb[4];
        #pragma unroll
        for (int ai = 0; ai < 2; ++ai)
            wa[ai] = *(const bhalf8*)(W2T + (size_t)(wcc * 32 + ai * 16 + lr) * H + ks * 32 + lk * 8);
        #pragma unroll
        for (int bj = 0; bj < 4; ++bj)
            xb[bj] = *(const bhalf8*)(&e1[(wr * 64 + bj * 16 + lr) * ESTRIDE + ks * 32 + lk * 8]);
        #pragma unroll
        for (int ai = 0; ai < 2; ++ai)
            #pragma unroll
            for (int bj = 0; bj < 4; ++bj)
                acc2[ai][bj] = __builtin_amdgcn_mfma_f32_16x16x32_bf16(wa[ai], xb[bj], acc2[ai][bj], 0, 0, 0);
    }

    float4 b2v[2];
    #pragma unroll
    for (int ai = 0; ai < 2; ++ai)
        b2v[ai] = *(const float4*)(b2 + wcc * 32 + ai * 16 + lk * 4);

    __syncthreads();   // all mm2 reads of e1 done; safe to overwrite with out-tile

    // ---- write bf16 out-tile to LDS ----
    #pragma unroll
    for (int ai = 0; ai < 2; ++ai)
        #pragma unroll
        for (int bj = 0; bj < 4; ++bj) {
            int rloc = wr * 64 + bj * 16 + lr;
            int colb = wcc * 32 + ai * 16 + lk * 4;
            ushort4 pk;
            pk.x = f2bf(silu_f(acc2[ai][bj][0] + b2v[ai].x));
            pk.y = f2bf(silu_f(acc2[ai][bj][1] + b2v[ai].y));
            pk.z = f2bf(silu_f(acc2[ai][bj][2] + b2v[ai].z));
            pk.w = f2bf(silu_f(acc2[ai][bj][3] + b2v[ai].w));
            *(ushort4*)(&e1[rloc * ESTRIDE + colb]) = pk;
        }
    __syncthreads();

    // ---- coalesced row scatter: 32 lanes x float4 = one 512B row per half-wave ----
    {
        int rr = tid >> 5;          // 0..15
        int cl = tid & 31;          // 32 lanes cover 128 cols as float4
        #pragma unroll
        for (int p = 0; p < 8; ++p) {
            int r = p * 16 + rr;
            int e = sE[r];
            ushort4 pk = *(ushort4*)(&e1[r * ESTRIDE + cl * 4]);
            float4 o;
            o.x = bf2f(pk.x); o.y = bf2f(pk.y); o.z = bf2f(pk.z); o.w = bf2f(pk.w);
            *(float4*)(&out_edge[(size_t)e * H + cl * 4]) = o;
        }
    }

    // ---- segmented reduction over dst runs -> sums (32 rows per thread) ----
    {
        int cc = tid & 127;
        int r0 = (tid >> 7) * 32;
        float acc = 0.0f;
        int curn = sDst[r0];
        for (int r = r0; r < r0 + 32; ++r) {
            int n = sDst[r];
            if (n != curn) {
                atomicAdd(&sums[(size_t)curn * H + cc], acc);
                acc = 0.0f;
                curn = n;
            }
            acc += bf2f(e1[r * ESTRIDE + cc]);
        }
        atomicAdd(&sums[(size_t)curn * H + cc], acc);
    }
}

// ---- node kernel: agg = sums/deg computed during staging ----
__global__ __launch_bounds__(256) void node_kernel(
    const float* __restrict__ nf, const float* __restrict__ sums,
    const int* __restrict__ cnt_i,
    const unsigned short* __restrict__ W3T, const float* __restrict__ b3,
    const unsigned short* __restrict__ W4T, const float* __restrict__ b4,
    float* __restrict__ out0)
{
    __shared__ unsigned short x_lds[64 * NSTRIDE];
    int tid = threadIdx.x;
    int nb = blockIdx.x * 64;

    // cols 0..127: nf (fp32 -> bf16)
    #pragma unroll
    for (int p = 0; p < 8; ++p) {
        int idx = p * 256 + tid;
        int n = idx >> 5, c = idx & 31;
        int node = nb + n; if (node >= NN) node = NN - 1;
        float4 v = *(const float4*)(nf + (size_t)node * H + c * 4);
        ushort4 o;
        o.x = f2bf(v.x); o.y = f2bf(v.y); o.z = f2bf(v.z); o.w = f2bf(v.w);
        *(ushort4*)(&x_lds[n * NSTRIDE + c * 4]) = o;
    }
    // cols 128..255: agg = sums/max(deg,1)
    #pragma unroll
    for (int p = 0; p < 8; ++p) {
        int idx = p * 256 + tid;
        int n = idx >> 5, c = idx & 31;
        int node = nb + n; if (node >= NN) node = NN - 1;
        float4 s = *(const float4*)(sums + (size_t)node * H + c * 4);
        float inv = 1.0f / fmaxf((float)cnt_i[node], 1.0f);
        ushort4 o;
        o.x = f2bf(s.x * inv); o.y = f2bf(s.y * inv);
        o.z = f2bf(s.z * inv); o.w = f2bf(s.w * inv);
        *(ushort4*)(&x_lds[n * NSTRIDE + 128 + c * 4]) = o;
    }
    __syncthreads();

    int wid = tid >> 6, lane = tid & 63;
    int wr = wid >> 1, wc = wid & 1;
    int lr = lane & 15, lk = lane >> 4;

    f32x4 acc[2][4];
    #pragma unroll
    for (int m = 0; m < 2; ++m)
        #pragma unroll
        for (int n = 0; n < 4; ++n) acc[m][n] = (f32x4){0.f, 0.f, 0.f, 0.f};

    #pragma unroll
    for (int ks = 0; ks < 8; ++ks) {
        bhalf8 a[2], b[4];
        #pragma unroll
        for (int m = 0; m < 2; ++m)
            a[m] = *(const bhalf8*)(&x_lds[(wr * 32 + m * 16 + lr) * NSTRIDE + ks * 32 + lk * 8]);
        #pragma unroll
        for (int n = 0; n < 4; ++n)
            b[n] = *(const bhalf8*)(W3T + (size_t)(wc * 64 + n * 16 + lr) * K3 + ks * 32 + lk * 8);
        #pragma unroll
        for (int m = 0; m < 2; ++m)
            #pragma unroll
            for (int n = 0; n < 4; ++n)
                acc[m][n] = __builtin_amdgcn_mfma_f32_16x16x32_bf16(a[m], b[n], acc[m][n], 0, 0, 0);
    }

    float bn3[4];
    #pragma unroll
    for (int n = 0; n < 4; ++n) bn3[n] = b3[wc * 64 + n * 16 + lr];

    __syncthreads();
    unsigned short* m_lds = x_lds;
    #pragma unroll
    for (int m = 0; m < 2; ++m)
        #pragma unroll
        for (int n = 0; n < 4; ++n)
            #pragma unroll
            for (int j = 0; j < 4; ++j) {
                int row = wr * 32 + m * 16 + lk * 4 + j;
                int col = wc * 64 + n * 16 + lr;
                m_lds[row * ESTRIDE + col] = f2bf(silu_f(acc[m][n][j] + bn3[n]));
            }
    __syncthreads();

    f32x4 acc2[2][4];
    #pragma unroll
    for (int m = 0; m < 2; ++m)
        #pragma unroll
        for (int n = 0; n < 4; ++n) acc2[m][n] = (f32x4){0.f, 0.f, 0.f, 0.f};

    #pragma unroll
    for (int ks = 0; ks < 4; ++ks) {
        bhalf8 a[2], b[4];
        #pragma unroll
        for (int m = 0; m < 2; ++m)
            a[m] = *(const bhalf8*)(&m_lds[(wr * 32 + m * 16 + lr) * ESTRIDE + ks * 32 + lk * 8]);
        #pragma unroll
        for (int n = 0; n < 4; ++n)
            b[n] = *(const bhalf8*)(W4T + (size_t)(wc * 64 + n * 16 + lr) * H + ks * 32 + lk * 8);
        #pragma unroll
        for (int m = 0; m < 2; ++m)
            #pragma unroll
            for (int n = 0; n < 4; ++n)
                acc2[m][n] = __builtin_amdgcn_mfma_f32_16x16x32_bf16(a[m], b[n], acc2[m][n], 0, 0, 0);
    }

    float bn4[4];
    #pragma unroll
    for (int n = 0; n < 4; ++n) bn4[n] = b4[wc * 64 + n * 16 + lr];

    #pragma unroll
    for (int m = 0; m < 2; ++m)
        #pragma unroll
        for (int n = 0; n < 4; ++n)
            #pragma unroll
            for (int j = 0; j < 4; ++j) {
                int row = wr * 32 + m * 16 + lk * 4 + j;
                int col = wc * 64 + n * 16 + lr;
                int node = nb + row;
                if (node < NN) {
                    float base = nf[(size_t)node * H + col];
                    out0[(size_t)node * H + col] = base + silu_f(acc2[m][n][j] + bn4[n]);
                }
            }
}

extern "C" void kernel_launch(void* const* d_in, const int* in_sizes, int n_in,
                              void* d_out, int out_size, void* d_ws, size_t ws_size,
                              hipStream_t stream) {
    const float* nf  = (const float*)d_in[0];
    const float* lat = (const float*)d_in[2];
    const float* fd  = (const float*)d_in[3];
    const float* W1  = (const float*)d_in[4];
    const float* b1  = (const float*)d_in[5];
    const float* W2  = (const float*)d_in[6];
    const float* b2  = (const float*)d_in[7];
    const float* W3  = (const float*)d_in[8];
    const float* b3  = (const float*)d_in[9];
    const float* W4  = (const float*)d_in[10];
    const float* b4  = (const float*)d_in[11];
    const int* ei    = (const int*)d_in[12];
    const int* e2g   = (const int*)d_in[13];

    float* out0     = (float*)d_out;
    float* out_edge = (float*)d_out + (size_t)NN * H;

    char* ws = (char*)d_ws;
    size_t off = 0;
    float* sums = (float*)(ws + off);                   off += (size_t)NN * H * 4;     // 25.6 MB (memset)
    int* cnt_i      = (int*)(ws + off);                 off += (size_t)NB * 256 * 4;   // (memset)
    int* fill       = (int*)(ws + off);                 off += (size_t)NB * 256 * 4;   // (memset)
    int* row_start  = (int*)(ws + off);                 off += (size_t)NB * 256 * 4;
    int* bsum       = (int*)(ws + off);                 off += 256 * 4;
    int* bbase      = (int*)(ws + off);                 off += 256 * 4;
    int* eidx       = (int*)(ws + off);                 off += (size_t)EE * 4;         // 3.2 MB
    unsigned short* P12  = (unsigned short*)(ws + off); off += (size_t)NN * 256 * 2;   // 25.6 MB
    unsigned short* W12T = (unsigned short*)(ws + off); off += (size_t)256 * H * 2;    // 64 KB
    unsigned short* W2T  = (unsigned short*)(ws + off); off += (size_t)H * H * 2;
    unsigned short* W3T  = (unsigned short*)(ws + off); off += (size_t)H * K3 * 2;
    unsigned short* W4T  = (unsigned short*)(ws + off); off += (size_t)H * H * 2;
    unsigned short* Qb   = (unsigned short*)(ws + off); off += (size_t)GG * H * 2;     // 64 KB
    const float* W1fd = W1 + (size_t)265 * H;   // fd rows of W1, used in-place

    // zero sums + cnt_i + fill (adjacent)
    (void)hipMemsetAsync(sums, 0, (size_t)NN * H * 4 + (size_t)NB * 256 * 4 * 2, stream);

    transpose_w_kernel<<<dim3(1, H), 256, 0, stream>>>(W2, W2T, H, H);
    transpose_w_kernel<<<dim3(1, H), 256, 0, stream>>>(W3, W3T, K3, K3);
    transpose_w_kernel<<<dim3(1, H), 256, 0, stream>>>(W4, W4T, H, H);
    w12t_kernel<<<256, 128, 0, stream>>>(W1, W12T);
    q_kernel<<<GG, 128, 0, stream>>>(lat, W1, b1, Qb);
    p12_kernel<<<(NN + 63) / 64, 256, 0, stream>>>(nf, W12T, P12);

    // CSR build
    count_kernel<<<(EE + 255) / 256, 256, 0, stream>>>(ei, cnt_i);
    scan1_kernel<<<NB, 256, 0, stream>>>(cnt_i, bsum);
    scan2_kernel<<<1, 256, 0, stream>>>(bsum, bbase);
    scan3_kernel<<<NB, 256, 0, stream>>>(cnt_i, bbase, row_start);
    scatter_kernel<<<(EE + 255) / 256, 256, 0, stream>>>(ei, row_start, fill, eidx);

    edge_kernel<<<EE / 128, 512, 0, stream>>>(P12, Qb, fd, W1fd, W2T, b2,
                                              ei, e2g, eidx, out_edge, sums);
    node_kernel<<<(NN + 63) / 64, 256, 0, stream>>>(nf, sums, cnt_i, W3T, b3, W4T, b4, out0);
}

// Round 10
// 396.826 us; speedup vs baseline: 1.5456x; 1.0218x over previous
//
#include <hip/hip_runtime.h>
#include <hip/hip_bf16.h>
#include <math.h>

#define H  128
#define NN 50000
#define EE 800000
#define GG 256
#define NB 196          // ceil(NN/256)

#define K3 256
#define NSTRIDE 264     // node x-tile LDS row stride
#define ESTRIDE 136     // hidden tile LDS row stride
#define PSTRIDE 136     // p12 staging stride

typedef __attribute__((ext_vector_type(8))) short bhalf8;
typedef __attribute__((ext_vector_type(4))) float f32x4;

__device__ __forceinline__ float silu_f(float x) {
    // x * rcp(1+e^-x): 1-ulp rcp is invisible after bf16 rounding
    return x * __builtin_amdgcn_rcpf(1.0f + __expf(-x));
}

// fp32 -> bf16 round-to-nearest-even
__device__ __forceinline__ unsigned short f2bf(float x) {
    unsigned int u = __float_as_uint(x);
    unsigned int r = 0x7fffu + ((u >> 16) & 1u);
    return (unsigned short)((u + r) >> 16);
}

// bf16 bits -> fp32
__device__ __forceinline__ float bf2f(unsigned short s) {
    return __uint_as_float(((unsigned int)s) << 16);
}

// ---- prep kernels ----

// W [K][128] fp32 -> WT [128][Kpad] bf16
__global__ void transpose_w_kernel(const float* __restrict__ W, unsigned short* __restrict__ WT,
                                   int K, int Kpad) {
    int k = blockIdx.x * blockDim.x + threadIdx.x;
    int c = blockIdx.y;
    if (k >= Kpad) return;
    WT[(size_t)c * Kpad + k] = (k < K) ? f2bf(W[(size_t)k * H + c]) : (unsigned short)0;
}

// W12T[j][k]: j<128 -> W1[k][j] (P1 part), j>=128 -> W1[128+k][j-128] (P2 part)
__global__ void w12t_kernel(const float* __restrict__ W1, unsigned short* __restrict__ W12T) {
    int j = blockIdx.x, k = threadIdx.x;   // 256 blocks x 128 threads
    float v = (j < 128) ? W1[(size_t)k * H + j] : W1[(size_t)(128 + k) * H + (j - 128)];
    W12T[(size_t)j * H + k] = f2bf(v);
}

// Q[g][c] = b1[c] + sum_r lat_ips[g][r] * W1[256+r][c]   (bf16 out)
__global__ void q_kernel(const float* __restrict__ lat, const float* __restrict__ W1,
                         const float* __restrict__ b1, unsigned short* __restrict__ Qb) {
    int g = blockIdx.x, c = threadIdx.x;   // 256 x 128
    const float* L = lat + g * 9;
    float q = b1[c];
    #pragma unroll
    for (int i = 0; i < 3; ++i)
        #pragma unroll
        for (int k = 0; k < 3; ++k) {
            float ip = L[i*3+0]*L[k*3+0] + L[i*3+1]*L[k*3+1] + L[i*3+2]*L[k*3+2];
            q += ip * W1[(size_t)(256 + i * 3 + k) * H + c];
        }
    Qb[(size_t)g * H + c] = f2bf(q);
}

// P12[n][0:128] = nf[n] @ W1a ; P12[n][128:256] = nf[n] @ W1b  (bf16 out)
__global__ __launch_bounds__(256) void p12_kernel(
    const float* __restrict__ nf, const unsigned short* __restrict__ W12T,
    unsigned short* __restrict__ P12)
{
    __shared__ unsigned short x_lds[64 * PSTRIDE];
    int tid = threadIdx.x;
    int nb = blockIdx.x * 64;

    #pragma unroll
    for (int p = 0; p < 8; ++p) {
        int idx = p * 256 + tid;
        int n = idx >> 5, c = idx & 31;
        int node = nb + n; if (node >= NN) node = NN - 1;
        float4 v = *(const float4*)(nf + (size_t)node * H + c * 4);
        ushort4 o;
        o.x = f2bf(v.x); o.y = f2bf(v.y); o.z = f2bf(v.z); o.w = f2bf(v.w);
        *(ushort4*)(&x_lds[n * PSTRIDE + c * 4]) = o;
    }
    __syncthreads();

    int wid = tid >> 6, lane = tid & 63;
    int wr = wid & 1, wc = wid >> 1;       // rows wr*32.., cols wc*128..
    int lr = lane & 15, lk = lane >> 4;

    f32x4 acc[2][8];
    #pragma unroll
    for (int m = 0; m < 2; ++m)
        #pragma unroll
        for (int n = 0; n < 8; ++n) acc[m][n] = (f32x4){0.f, 0.f, 0.f, 0.f};

    #pragma unroll
    for (int ks = 0; ks < 4; ++ks) {
        bhalf8 a[2], b[8];
        #pragma unroll
        for (int m = 0; m < 2; ++m)
            a[m] = *(const bhalf8*)(&x_lds[(wr * 32 + m * 16 + lr) * PSTRIDE + ks * 32 + lk * 8]);
        #pragma unroll
        for (int n = 0; n < 8; ++n)
            b[n] = *(const bhalf8*)(W12T + (size_t)(wc * 128 + n * 16 + lr) * H + ks * 32 + lk * 8);
        #pragma unroll
        for (int m = 0; m < 2; ++m)
            #pragma unroll
            for (int n = 0; n < 8; ++n)
                acc[m][n] = __builtin_amdgcn_mfma_f32_16x16x32_bf16(a[m], b[n], acc[m][n], 0, 0, 0);
    }

    #pragma unroll
    for (int m = 0; m < 2; ++m)
        #pragma unroll
        for (int n = 0; n < 8; ++n)
            #pragma unroll
            for (int j = 0; j < 4; ++j) {
                int row = wr * 32 + m * 16 + lk * 4 + j;
                int col = wc * 128 + n * 16 + lr;
                int node = nb + row;
                if (node < NN) P12[(size_t)node * 256 + col] = f2bf(acc[m][n][j]);
            }
}

// ---- CSR build ----

__global__ void count_kernel(const int* __restrict__ ei, int* __restrict__ cnt_i) {
    int e = blockIdx.x * blockDim.x + threadIdx.x;
    if (e < EE) atomicAdd(&cnt_i[ei[EE + e]], 1);
}

__global__ void scan1_kernel(const int* __restrict__ cnt_i, int* __restrict__ bsum) {
    __shared__ int red[256];
    int b = blockIdx.x, t = threadIdx.x;
    int n = b * 256 + t;
    red[t] = (n < NN) ? cnt_i[n] : 0;
    __syncthreads();
    for (int s = 128; s > 0; s >>= 1) {
        if (t < s) red[t] += red[t + s];
        __syncthreads();
    }
    if (t == 0) bsum[b] = red[0];
}

__global__ void scan2_kernel(const int* __restrict__ bsum, int* __restrict__ bbase) {
    __shared__ int tmp[256];
    int t = threadIdx.x;
    int c = (t < NB) ? bsum[t] : 0;
    tmp[t] = c;
    __syncthreads();
    for (int s = 1; s < 256; s <<= 1) {
        int u = (t >= s) ? tmp[t - s] : 0;
        __syncthreads();
        tmp[t] += u;
        __syncthreads();
    }
    if (t < NB) bbase[t] = tmp[t] - c;   // exclusive
}

__global__ void scan3_kernel(const int* __restrict__ cnt_i, const int* __restrict__ bbase,
                             int* __restrict__ row_start) {
    __shared__ int tmp[256];
    int b = blockIdx.x, t = threadIdx.x;
    int n = b * 256 + t;
    int c = (n < NN) ? cnt_i[n] : 0;
    tmp[t] = c;
    __syncthreads();
    for (int s = 1; s < 256; s <<= 1) {
        int u = (t >= s) ? tmp[t - s] : 0;
        __syncthreads();
        tmp[t] += u;
        __syncthreads();
    }
    if (n < NN) row_start[n] = bbase[b] + tmp[t] - c;   // exclusive
}

__global__ void scatter_kernel(const int* __restrict__ ei, const int* __restrict__ row_start,
                               int* __restrict__ fill, int* __restrict__ eidx) {
    int e = blockIdx.x * blockDim.x + threadIdx.x;
    if (e < EE) {
        int d = ei[EE + e];
        int pos = row_start[d] + atomicAdd(&fill[d], 1);
        eidx[pos] = e;
    }
}

// ---- edge kernel v7: CSR-ordered, prefetched gathers, paired-col reduce ----
__global__ __launch_bounds__(512, 5) void edge_kernel(
    const unsigned short* __restrict__ P12, const unsigned short* __restrict__ Qb,
    const float* __restrict__ fdg, const float* __restrict__ W1fd,
    const unsigned short* __restrict__ W2T, const float* __restrict__ b2,
    const int* __restrict__ ei, const int* __restrict__ e2g,
    const int* __restrict__ eidx,
    float* __restrict__ out_edge, float* __restrict__ sums)
{
    __shared__ unsigned short e1[128 * ESTRIDE];   // 34.8 KB; reused as out-tile (bf16)
    __shared__ int sE[128], sSrc[128], sDst[128], sG[128];
    __shared__ float sFd[128 * 3];

    int tid = threadIdx.x;
    int eb = blockIdx.x * 128;

    if (tid < 128) sE[tid] = eidx[eb + tid];
    __syncthreads();
    if (tid < 128) {
        int e = sE[tid];
        sSrc[tid] = ei[e];
        sG[tid]   = e2g[e];
    } else if (tid < 256) {
        sDst[tid - 128] = ei[EE + sE[tid - 128]];
    } else if (tid < 384) {
        int r = tid - 256;
        int e = sE[r];
        sFd[r * 3 + 0] = fdg[(size_t)e * 3 + 0];
        sFd[r * 3 + 1] = fdg[(size_t)e * 3 + 1];
        sFd[r * 3 + 2] = fdg[(size_t)e * 3 + 2];
    }
    __syncthreads();

    int c = tid & 15;
    // per-lane W1_fd columns (3 rows x 8 cols), L1-cached
    float4 wf[3][2];
    #pragma unroll
    for (int k = 0; k < 3; ++k)
        #pragma unroll
        for (int h = 0; h < 2; ++h)
            wf[k][h] = *(const float4*)(W1fd + k * H + c * 8 + h * 4);

    // ---- prefetch all P12 gathers (8 independent 16B loads in flight) ----
    uint4 P1v[4], P2v[4];
    #pragma unroll
    for (int p = 0; p < 4; ++p) {
        int r = p * 32 + (tid >> 4);
        P1v[p] = *(const uint4*)(P12 + (size_t)sSrc[r] * 256 + c * 8);
        P2v[p] = *(const uint4*)(P12 + (size_t)sDst[r] * 256 + 128 + c * 8);
    }

    // ---- build e1[128][128] (bf16): 4 rows per thread ----
    #pragma unroll
    for (int p = 0; p < 4; ++p) {
        int r = p * 32 + (tid >> 4);
        int g = sG[r];
        bhalf8 p1 = *(const bhalf8*)(&P1v[p]);
        bhalf8 p2 = *(const bhalf8*)(&P2v[p]);
        bhalf8 qv = *(const bhalf8*)(Qb + (size_t)g * H + c * 8);
        float f0 = sFd[r * 3 + 0], f1 = sFd[r * 3 + 1], f2v = sFd[r * 3 + 2];
        unsigned int w[4];
        #pragma unroll
        for (int jj = 0; jj < 4; ++jj) {
            unsigned int lo = 0, hi = 0;
            #pragma unroll
            for (int half = 0; half < 2; ++half) {
                int j = jj * 2 + half;
                const float* wfp = (const float*)&wf[0][0];
                float wv0 = wfp[j];
                float wv1 = wfp[8 + j];
                float wv2 = wfp[16 + j];
                float v = bf2f((unsigned short)p1[j]) + bf2f((unsigned short)p2[j])
                        + bf2f((unsigned short)qv[j])
                        + f0 * wv0 + f1 * wv1 + f2v * wv2;
                unsigned int us = f2bf(silu_f(v));
                if (half == 0) lo = us; else hi = us;
            }
            w[jj] = lo | (hi << 16);
        }
        uint4 pk; pk.x = w[0]; pk.y = w[1]; pk.z = w[2]; pk.w = w[3];
        *(uint4*)(&e1[r * ESTRIDE + c * 8]) = pk;
    }
    __syncthreads();

    // ---- mm2: 8 waves, each 64 rows x 32 cols ----
    int wid = tid >> 6, lane = tid & 63;
    int wr = wid >> 2, wcc = wid & 3;   // rows wr*64.., cols wcc*32..
    int lr = lane & 15, lk = lane >> 4;

    f32x4 acc2[2][4];
    #pragma unroll
    for (int a = 0; a < 2; ++a)
        #pragma unroll
        for (int b = 0; b < 4; ++b) acc2[a][b] = (f32x4){0.f, 0.f, 0.f, 0.f};

    #pragma unroll
    for (int ks = 0; ks < 4; ++ks) {
        bhalf8 wa[2], xb[4];
        #pragma unroll
        for (int ai = 0; ai < 2; ++ai)
            wa[ai] = *(const bhalf8*)(W2T + (size_t)(wcc * 32 + ai * 16 + lr) * H + ks * 32 + lk * 8);
        #pragma unroll
        for (int bj = 0; bj < 4; ++bj)
            xb[bj] = *(const bhalf8*)(&e1[(wr * 64 + bj * 16 + lr) * ESTRIDE + ks * 32 + lk * 8]);
        #pragma unroll
        for (int ai = 0; ai < 2; ++ai)
            #pragma unroll
            for (int bj = 0; bj < 4; ++bj)
                acc2[ai][bj] = __builtin_amdgcn_mfma_f32_16x16x32_bf16(wa[ai], xb[bj], acc2[ai][bj], 0, 0, 0);
    }

    float4 b2v[2];
    #pragma unroll
    for (int ai = 0; ai < 2; ++ai)
        b2v[ai] = *(const float4*)(b2 + wcc * 32 + ai * 16 + lk * 4);

    __syncthreads();   // all mm2 reads of e1 done; safe to overwrite with out-tile

    // ---- write bf16 out-tile to LDS ----
    #pragma unroll
    for (int ai = 0; ai < 2; ++ai)
        #pragma unroll
        for (int bj = 0; bj < 4; ++bj) {
            int rloc = wr * 64 + bj * 16 + lr;
            int colb = wcc * 32 + ai * 16 + lk * 4;
            ushort4 pk;
            pk.x = f2bf(silu_f(acc2[ai][bj][0] + b2v[ai].x));
            pk.y = f2bf(silu_f(acc2[ai][bj][1] + b2v[ai].y));
            pk.z = f2bf(silu_f(acc2[ai][bj][2] + b2v[ai].z));
            pk.w = f2bf(silu_f(acc2[ai][bj][3] + b2v[ai].w));
            *(ushort4*)(&e1[rloc * ESTRIDE + colb]) = pk;
        }
    __syncthreads();

    // ---- coalesced row scatter: 32 lanes x float4 = one 512B row ----
    {
        int rr = tid >> 5;          // 0..15
        int cl = tid & 31;          // 32 lanes cover 128 cols as float4
        #pragma unroll
        for (int p = 0; p < 8; ++p) {
            int r = p * 16 + rr;
            int e = sE[r];
            ushort4 pk = *(ushort4*)(&e1[r * ESTRIDE + cl * 4]);
            float4 o;
            o.x = bf2f(pk.x); o.y = bf2f(pk.y); o.z = bf2f(pk.z); o.w = bf2f(pk.w);
            *(float4*)(&out_edge[(size_t)e * H + cl * 4]) = o;
        }
    }

    // ---- segmented reduction over dst runs -> sums (2 cols x 16 rows/thread) ----
    {
        int cp = (tid & 63) * 2;        // column pair
        int r0 = (tid >> 6) * 16;       // row chunk
        float a0 = 0.0f, a1 = 0.0f;
        int curn = sDst[r0];
        for (int r = r0; r < r0 + 16; ++r) {
            int n = sDst[r];
            if (n != curn) {
                atomicAdd(&sums[(size_t)curn * H + cp], a0);
                atomicAdd(&sums[(size_t)curn * H + cp + 1], a1);
                a0 = a1 = 0.0f;
                curn = n;
            }
            unsigned int u = *(const unsigned int*)(&e1[r * ESTRIDE + cp]);
            a0 += bf2f((unsigned short)(u & 0xffffu));
            a1 += bf2f((unsigned short)(u >> 16));
        }
        atomicAdd(&sums[(size_t)curn * H + cp], a0);
        atomicAdd(&sums[(size_t)curn * H + cp + 1], a1);
    }
}

// ---- node kernel: agg = sums/deg computed during staging ----
__global__ __launch_bounds__(256) void node_kernel(
    const float* __restrict__ nf, const float* __restrict__ sums,
    const int* __restrict__ cnt_i,
    const unsigned short* __restrict__ W3T, const float* __restrict__ b3,
    const unsigned short* __restrict__ W4T, const float* __restrict__ b4,
    float* __restrict__ out0)
{
    __shared__ unsigned short x_lds[64 * NSTRIDE];
    int tid = threadIdx.x;
    int nb = blockIdx.x * 64;

    // cols 0..127: nf (fp32 -> bf16)
    #pragma unroll
    for (int p = 0; p < 8; ++p) {
        int idx = p * 256 + tid;
        int n = idx >> 5, c = idx & 31;
        int node = nb + n; if (node >= NN) node = NN - 1;
        float4 v = *(const float4*)(nf + (size_t)node * H + c * 4);
        ushort4 o;
        o.x = f2bf(v.x); o.y = f2bf(v.y); o.z = f2bf(v.z); o.w = f2bf(v.w);
        *(ushort4*)(&x_lds[n * NSTRIDE + c * 4]) = o;
    }
    // cols 128..255: agg = sums/max(deg,1)
    #pragma unroll
    for (int p = 0; p < 8; ++p) {
        int idx = p * 256 + tid;
        int n = idx >> 5, c = idx & 31;
        int node = nb + n; if (node >= NN) node = NN - 1;
        float4 s = *(const float4*)(sums + (size_t)node * H + c * 4);
        float inv = 1.0f / fmaxf((float)cnt_i[node], 1.0f);
        ushort4 o;
        o.x = f2bf(s.x * inv); o.y = f2bf(s.y * inv);
        o.z = f2bf(s.z * inv); o.w = f2bf(s.w * inv);
        *(ushort4*)(&x_lds[n * NSTRIDE + 128 + c * 4]) = o;
    }
    __syncthreads();

    int wid = tid >> 6, lane = tid & 63;
    int wr = wid >> 1, wc = wid & 1;
    int lr = lane & 15, lk = lane >> 4;

    f32x4 acc[2][4];
    #pragma unroll
    for (int m = 0; m < 2; ++m)
        #pragma unroll
        for (int n = 0; n < 4; ++n) acc[m][n] = (f32x4){0.f, 0.f, 0.f, 0.f};

    #pragma unroll
    for (int ks = 0; ks < 8; ++ks) {
        bhalf8 a[2], b[4];
        #pragma unroll
        for (int m = 0; m < 2; ++m)
            a[m] = *(const bhalf8*)(&x_lds[(wr * 32 + m * 16 + lr) * NSTRIDE + ks * 32 + lk * 8]);
        #pragma unroll
        for (int n = 0; n < 4; ++n)
            b[n] = *(const bhalf8*)(W3T + (size_t)(wc * 64 + n * 16 + lr) * K3 + ks * 32 + lk * 8);
        #pragma unroll
        for (int m = 0; m < 2; ++m)
            #pragma unroll
            for (int n = 0; n < 4; ++n)
                acc[m][n] = __builtin_amdgcn_mfma_f32_16x16x32_bf16(a[m], b[n], acc[m][n], 0, 0, 0);
    }

    float bn3[4];
    #pragma unroll
    for (int n = 0; n < 4; ++n) bn3[n] = b3[wc * 64 + n * 16 + lr];

    __syncthreads();
    unsigned short* m_lds = x_lds;
    #pragma unroll
    for (int m = 0; m < 2; ++m)
        #pragma unroll
        for (int n = 0; n < 4; ++n)
            #pragma unroll
            for (int j = 0; j < 4; ++j) {
                int row = wr * 32 + m * 16 + lk * 4 + j;
                int col = wc * 64 + n * 16 + lr;
                m_lds[row * ESTRIDE + col] = f2bf(silu_f(acc[m][n][j] + bn3[n]));
            }
    __syncthreads();

    f32x4 acc2[2][4];
    #pragma unroll
    for (int m = 0; m < 2; ++m)
        #pragma unroll
        for (int n = 0; n < 4; ++n) acc2[m][n] = (f32x4){0.f, 0.f, 0.f, 0.f};

    #pragma unroll
    for (int ks = 0; ks < 4; ++ks) {
        bhalf8 a[2], b[4];
        #pragma unroll
        for (int m = 0; m < 2; ++m)
            a[m] = *(const bhalf8*)(&m_lds[(wr * 32 + m * 16 + lr) * ESTRIDE + ks * 32 + lk * 8]);
        #pragma unroll
        for (int n = 0; n < 4; ++n)
            b[n] = *(const bhalf8*)(W4T + (size_t)(wc * 64 + n * 16 + lr) * H + ks * 32 + lk * 8);
        #pragma unroll
        for (int m = 0; m < 2; ++m)
            #pragma unroll
            for (int n = 0; n < 4; ++n)
                acc2[m][n] = __builtin_amdgcn_mfma_f32_16x16x32_bf16(a[m], b[n], acc2[m][n], 0, 0, 0);
    }

    float bn4[4];
    #pragma unroll
    for (int n = 0; n < 4; ++n) bn4[n] = b4[wc * 64 + n * 16 + lr];

    #pragma unroll
    for (int m = 0; m < 2; ++m)
        #pragma unroll
        for (int n = 0; n < 4; ++n)
            #pragma unroll
            for (int j = 0; j < 4; ++j) {
                int row = wr * 32 + m * 16 + lk * 4 + j;
                int col = wc * 64 + n * 16 + lr;
                int node = nb + row;
                if (node < NN) {
                    float base = nf[(size_t)node * H + col];
                    out0[(size_t)node * H + col] = base + silu_f(acc2[m][n][j] + bn4[n]);
                }
            }
}

extern "C" void kernel_launch(void* const* d_in, const int* in_sizes, int n_in,
                              void* d_out, int out_size, void* d_ws, size_t ws_size,
                              hipStream_t stream) {
    const float* nf  = (const float*)d_in[0];
    const float* lat = (const float*)d_in[2];
    const float* fd  = (const float*)d_in[3];
    const float* W1  = (const float*)d_in[4];
    const float* b1  = (const float*)d_in[5];
    const float* W2  = (const float*)d_in[6];
    const float* b2  = (const float*)d_in[7];
    const float* W3  = (const float*)d_in[8];
    const float* b3  = (const float*)d_in[9];
    const float* W4  = (const float*)d_in[10];
    const float* b4  = (const float*)d_in[11];
    const int* ei    = (const int*)d_in[12];
    const int* e2g   = (const int*)d_in[13];

    float* out0     = (float*)d_out;
    float* out_edge = (float*)d_out + (size_t)NN * H;

    char* ws = (char*)d_ws;
    size_t off = 0;
    float* sums = (float*)(ws + off);                   off += (size_t)NN * H * 4;     // 25.6 MB (memset)
    int* cnt_i      = (int*)(ws + off);                 off += (size_t)NB * 256 * 4;   // (memset)
    int* fill       = (int*)(ws + off);                 off += (size_t)NB * 256 * 4;   // (memset)
    int* row_start  = (int*)(ws + off);                 off += (size_t)NB * 256 * 4;
    int* bsum       = (int*)(ws + off);                 off += 256 * 4;
    int* bbase      = (int*)(ws + off);                 off += 256 * 4;
    int* eidx       = (int*)(ws + off);                 off += (size_t)EE * 4;         // 3.2 MB
    unsigned short* P12  = (unsigned short*)(ws + off); off += (size_t)NN * 256 * 2;   // 25.6 MB
    unsigned short* W12T = (unsigned short*)(ws + off); off += (size_t)256 * H * 2;    // 64 KB
    unsigned short* W2T  = (unsigned short*)(ws + off); off += (size_t)H * H * 2;
    unsigned short* W3T  = (unsigned short*)(ws + off); off += (size_t)H * K3 * 2;
    unsigned short* W4T  = (unsigned short*)(ws + off); off += (size_t)H * H * 2;
    unsigned short* Qb   = (unsigned short*)(ws + off); off += (size_t)GG * H * 2;     // 64 KB
    const float* W1fd = W1 + (size_t)265 * H;   // fd rows of W1, used in-place

    // zero sums + cnt_i + fill (adjacent)
    (void)hipMemsetAsync(sums, 0, (size_t)NN * H * 4 + (size_t)NB * 256 * 4 * 2, stream);

    transpose_w_kernel<<<dim3(1, H), 256, 0, stream>>>(W2, W2T, H, H);
    transpose_w_kernel<<<dim3(1, H), 256, 0, stream>>>(W3, W3T, K3, K3);
    transpose_w_kernel<<<dim3(1, H), 256, 0, stream>>>(W4, W4T, H, H);
    w12t_kernel<<<256, 128, 0, stream>>>(W1, W12T);
    q_kernel<<<GG, 128, 0, stream>>>(lat, W1, b1, Qb);
    p12_kernel<<<(NN + 63) / 64, 256, 0, stream>>>(nf, W12T, P12);

    // CSR build
    count_kernel<<<(EE + 255) / 256, 256, 0, stream>>>(ei, cnt_i);
    scan1_kernel<<<NB, 256, 0, stream>>>(cnt_i, bsum);
    scan2_kernel<<<1, 256, 0, stream>>>(bsum, bbase);
    scan3_kernel<<<NB, 256, 0, stream>>>(cnt_i, bbase, row_start);
    scatter_kernel<<<(EE + 255) / 256, 256, 0, stream>>>(ei, row_start, fill, eidx);

    edge_kernel<<<EE / 128, 512, 0, stream>>>(P12, Qb, fd, W1fd, W2T, b2,
                                              ei, e2g, eidx, out_edge, sums);
    node_kernel<<<(NN + 63) / 64, 256, 0, stream>>>(nf, sums, cnt_i, W3T, b3, W4T, b4, out0);
}

// Round 12
// 385.516 us; speedup vs baseline: 1.5909x; 1.0293x over previous
//
#include <hip/hip_runtime.h>
#include <hip/hip_bf16.h>
#include <math.h>

#define H  128
#define NN 50000
#define EE 800000
#define GG 256
#define NB 196          // ceil(NN/256)

#define K3 256
#define NSTRIDE 264     // node x-tile LDS row stride
#define ESTRIDE 136     // hidden tile LDS row stride
#define PSTRIDE 136     // p12 staging stride

typedef __attribute__((ext_vector_type(8))) short bhalf8;
typedef __attribute__((ext_vector_type(4))) float f32x4;

__device__ __forceinline__ float silu_f(float x) {
    // x * rcp(1 + 2^(-x*log2e)); 1-ulp rcp invisible after bf16 rounding
    return x * __builtin_amdgcn_rcpf(1.0f + exp2f(x * -1.442695041f));
}

// fp32 -> bf16 round-to-nearest-even
__device__ __forceinline__ unsigned short f2bf(float x) {
    unsigned int u = __float_as_uint(x);
    unsigned int r = 0x7fffu + ((u >> 16) & 1u);
    return (unsigned short)((u + r) >> 16);
}

// bf16 bits -> fp32
__device__ __forceinline__ float bf2f(unsigned short s) {
    return __uint_as_float(((unsigned int)s) << 16);
}

// ---- merged prep kernel: W2T/W4T/W3T/W12T/Qb + degree count ----
// grid: [0,64) W2T | [64,128) W4T | [128,256) W3T | [256,384) W12T
//       [384,512) Qb | [512, 512+3125) count
__global__ __launch_bounds__(256) void prep_kernel(
    const float* __restrict__ W1, const float* __restrict__ b1,
    const float* __restrict__ W2, const float* __restrict__ W3,
    const float* __restrict__ W4, const float* __restrict__ lat,
    const int* __restrict__ ei,
    unsigned short* __restrict__ W12T, unsigned short* __restrict__ W2T,
    unsigned short* __restrict__ W3T, unsigned short* __restrict__ W4T,
    unsigned short* __restrict__ Qb, int* __restrict__ cnt_i)
{
    int bid = blockIdx.x, tid = threadIdx.x;
    if (bid < 64) {
        int c = bid * 2 + (tid >> 7), k = tid & 127;
        W2T[(size_t)c * H + k] = f2bf(W2[(size_t)k * H + c]);
    } else if (bid < 128) {
        int c = (bid - 64) * 2 + (tid >> 7), k = tid & 127;
        W4T[(size_t)c * H + k] = f2bf(W4[(size_t)k * H + c]);
    } else if (bid < 256) {
        int c = bid - 128, k = tid;
        W3T[(size_t)c * K3 + k] = f2bf(W3[(size_t)k * H + c]);
    } else if (bid < 384) {
        int j = (bid - 256) * 2 + (tid >> 7), k = tid & 127;
        float v = (j < 128) ? W1[(size_t)k * H + j] : W1[(size_t)(128 + k) * H + (j - 128)];
        W12T[(size_t)j * H + k] = f2bf(v);
    } else if (bid < 512) {
        int g = (bid - 384) * 2 + (tid >> 7), c = tid & 127;
        const float* L = lat + g * 9;
        float q = b1[c];
        #pragma unroll
        for (int i = 0; i < 3; ++i)
            #pragma unroll
            for (int k = 0; k < 3; ++k) {
                float ip = L[i*3+0]*L[k*3+0] + L[i*3+1]*L[k*3+1] + L[i*3+2]*L[k*3+2];
                q += ip * W1[(size_t)(256 + i * 3 + k) * H + c];
            }
        Qb[(size_t)g * H + c] = f2bf(q);
    } else {
        int e = (bid - 512) * 256 + tid;
        if (e < EE) atomicAdd(&cnt_i[ei[EE + e]], 1);
    }
}

// P12[n][0:128] = nf[n] @ W1a ; P12[n][128:256] = nf[n] @ W1b  (bf16 out)
__global__ __launch_bounds__(256) void p12_kernel(
    const float* __restrict__ nf, const unsigned short* __restrict__ W12T,
    unsigned short* __restrict__ P12)
{
    __shared__ unsigned short x_lds[64 * PSTRIDE];
    int tid = threadIdx.x;
    int nb = blockIdx.x * 64;

    #pragma unroll
    for (int p = 0; p < 8; ++p) {
        int idx = p * 256 + tid;
        int n = idx >> 5, c = idx & 31;
        int node = nb + n; if (node >= NN) node = NN - 1;
        float4 v = *(const float4*)(nf + (size_t)node * H + c * 4);
        ushort4 o;
        o.x = f2bf(v.x); o.y = f2bf(v.y); o.z = f2bf(v.z); o.w = f2bf(v.w);
        *(ushort4*)(&x_lds[n * PSTRIDE + c * 4]) = o;
    }
    __syncthreads();

    int wid = tid >> 6, lane = tid & 63;
    int wr = wid & 1, wc = wid >> 1;       // rows wr*32.., cols wc*128..
    int lr = lane & 15, lk = lane >> 4;

    f32x4 acc[2][8];
    #pragma unroll
    for (int m = 0; m < 2; ++m)
        #pragma unroll
        for (int n = 0; n < 8; ++n) acc[m][n] = (f32x4){0.f, 0.f, 0.f, 0.f};

    #pragma unroll
    for (int ks = 0; ks < 4; ++ks) {
        bhalf8 a[2], b[8];
        #pragma unroll
        for (int m = 0; m < 2; ++m)
            a[m] = *(const bhalf8*)(&x_lds[(wr * 32 + m * 16 + lr) * PSTRIDE + ks * 32 + lk * 8]);
        #pragma unroll
        for (int n = 0; n < 8; ++n)
            b[n] = *(const bhalf8*)(W12T + (size_t)(wc * 128 + n * 16 + lr) * H + ks * 32 + lk * 8);
        #pragma unroll
        for (int m = 0; m < 2; ++m)
            #pragma unroll
            for (int n = 0; n < 8; ++n)
                acc[m][n] = __builtin_amdgcn_mfma_f32_16x16x32_bf16(a[m], b[n], acc[m][n], 0, 0, 0);
    }

    #pragma unroll
    for (int m = 0; m < 2; ++m)
        #pragma unroll
        for (int n = 0; n < 8; ++n)
            #pragma unroll
            for (int j = 0; j < 4; ++j) {
                int row = wr * 32 + m * 16 + lk * 4 + j;
                int col = wc * 128 + n * 16 + lr;
                int node = nb + row;
                if (node < NN) P12[(size_t)node * 256 + col] = f2bf(acc[m][n][j]);
            }
}

// ---- CSR build ----

__global__ void scan1_kernel(const int* __restrict__ cnt_i, int* __restrict__ bsum) {
    __shared__ int red[256];
    int b = blockIdx.x, t = threadIdx.x;
    int n = b * 256 + t;
    red[t] = (n < NN) ? cnt_i[n] : 0;
    __syncthreads();
    for (int s = 128; s > 0; s >>= 1) {
        if (t < s) red[t] += red[t + s];
        __syncthreads();
    }
    if (t == 0) bsum[b] = red[0];
}

__global__ void scan2_kernel(const int* __restrict__ bsum, int* __restrict__ bbase) {
    __shared__ int tmp[256];
    int t = threadIdx.x;
    int c = (t < NB) ? bsum[t] : 0;
    tmp[t] = c;
    __syncthreads();
    for (int s = 1; s < 256; s <<= 1) {
        int u = (t >= s) ? tmp[t - s] : 0;
        __syncthreads();
        tmp[t] += u;
        __syncthreads();
    }
    if (t < NB) bbase[t] = tmp[t] - c;   // exclusive
}

__global__ void scan3_kernel(const int* __restrict__ cnt_i, const int* __restrict__ bbase,
                             int* __restrict__ row_start) {
    __shared__ int tmp[256];
    int b = blockIdx.x, t = threadIdx.x;
    int n = b * 256 + t;
    int c = (n < NN) ? cnt_i[n] : 0;
    tmp[t] = c;
    __syncthreads();
    for (int s = 1; s < 256; s <<= 1) {
        int u = (t >= s) ? tmp[t - s] : 0;
        __syncthreads();
        tmp[t] += u;
        __syncthreads();
    }
    if (n < NN) row_start[n] = bbase[b] + tmp[t] - c;   // exclusive
}

__global__ void scatter_kernel(const int* __restrict__ ei, const int* __restrict__ row_start,
                               int* __restrict__ fill, int* __restrict__ eidx) {
    int e = blockIdx.x * blockDim.x + threadIdx.x;
    if (e < EE) {
        int d = ei[EE + e];
        int pos = row_start[d] + atomicAdd(&fill[d], 1);
        eidx[pos] = e;
    }
}

// ---- edge kernel v8: CSR-ordered, prefetched gathers, NT out_edge stores ----
__global__ __launch_bounds__(512, 5) void edge_kernel(
    const unsigned short* __restrict__ P12, const unsigned short* __restrict__ Qb,
    const float* __restrict__ fdg, const float* __restrict__ W1fd,
    const unsigned short* __restrict__ W2T, const float* __restrict__ b2,
    const int* __restrict__ ei, const int* __restrict__ e2g,
    const int* __restrict__ eidx,
    float* __restrict__ out_edge, float* __restrict__ sums)
{
    __shared__ unsigned short e1[128 * ESTRIDE];   // 34.8 KB; reused as out-tile (bf16)
    __shared__ int sE[128], sSrc[128], sDst[128], sG[128];
    __shared__ float sFd[128 * 3];

    int tid = threadIdx.x;
    int eb = blockIdx.x * 128;

    if (tid < 128) sE[tid] = eidx[eb + tid];
    __syncthreads();
    if (tid < 128) {
        int e = sE[tid];
        sSrc[tid] = ei[e];
        sG[tid]   = e2g[e];
    } else if (tid < 256) {
        sDst[tid - 128] = ei[EE + sE[tid - 128]];
    } else if (tid < 384) {
        int r = tid - 256;
        int e = sE[r];
        sFd[r * 3 + 0] = fdg[(size_t)e * 3 + 0];
        sFd[r * 3 + 1] = fdg[(size_t)e * 3 + 1];
        sFd[r * 3 + 2] = fdg[(size_t)e * 3 + 2];
    }
    __syncthreads();

    int c = tid & 15;
    // per-lane W1_fd columns (3 rows x 8 cols), L1-cached
    float4 wf[3][2];
    #pragma unroll
    for (int k = 0; k < 3; ++k)
        #pragma unroll
        for (int h = 0; h < 2; ++h)
            wf[k][h] = *(const float4*)(W1fd + k * H + c * 8 + h * 4);

    // ---- prefetch all P12 gathers (8 independent 16B loads in flight) ----
    uint4 P1v[4], P2v[4];
    #pragma unroll
    for (int p = 0; p < 4; ++p) {
        int r = p * 32 + (tid >> 4);
        P1v[p] = *(const uint4*)(P12 + (size_t)sSrc[r] * 256 + c * 8);
        P2v[p] = *(const uint4*)(P12 + (size_t)sDst[r] * 256 + 128 + c * 8);
    }

    // ---- build e1[128][128] (bf16): 4 rows per thread ----
    #pragma unroll
    for (int p = 0; p < 4; ++p) {
        int r = p * 32 + (tid >> 4);
        int g = sG[r];
        bhalf8 p1 = *(const bhalf8*)(&P1v[p]);
        bhalf8 p2 = *(const bhalf8*)(&P2v[p]);
        bhalf8 qv = *(const bhalf8*)(Qb + (size_t)g * H + c * 8);
        float f0 = sFd[r * 3 + 0], f1 = sFd[r * 3 + 1], f2v = sFd[r * 3 + 2];
        unsigned int w[4];
        #pragma unroll
        for (int jj = 0; jj < 4; ++jj) {
            unsigned int lo = 0, hi = 0;
            #pragma unroll
            for (int half = 0; half < 2; ++half) {
                int j = jj * 2 + half;
                const float* wfp = (const float*)&wf[0][0];
                float wv0 = wfp[j];
                float wv1 = wfp[8 + j];
                float wv2 = wfp[16 + j];
                float v = bf2f((unsigned short)p1[j]) + bf2f((unsigned short)p2[j])
                        + bf2f((unsigned short)qv[j])
                        + f0 * wv0 + f1 * wv1 + f2v * wv2;
                unsigned int us = f2bf(silu_f(v));
                if (half == 0) lo = us; else hi = us;
            }
            w[jj] = lo | (hi << 16);
        }
        uint4 pk; pk.x = w[0]; pk.y = w[1]; pk.z = w[2]; pk.w = w[3];
        *(uint4*)(&e1[r * ESTRIDE + c * 8]) = pk;
    }
    __syncthreads();

    // ---- mm2: 8 waves, each 64 rows x 32 cols ----
    int wid = tid >> 6, lane = tid & 63;
    int wr = wid >> 2, wcc = wid & 3;   // rows wr*64.., cols wcc*32..
    int lr = lane & 15, lk = lane >> 4;

    f32x4 acc2[2][4];
    #pragma unroll
    for (int a = 0; a < 2; ++a)
        #pragma unroll
        for (int b = 0; b < 4; ++b) acc2[a][b] = (f32x4){0.f, 0.f, 0.f, 0.f};

    #pragma unroll
    for (int ks = 0; ks < 4; ++ks) {
        bhalf8 wa[2], xb[4];
        #pragma unroll
        for (int ai = 0; ai < 2; ++ai)
            wa[ai] = *(const bhalf8*)(W2T + (size_t)(wcc * 32 + ai * 16 + lr) * H + ks * 32 + lk * 8);
        #pragma unroll
        for (int bj = 0; bj < 4; ++bj)
            xb[bj] = *(const bhalf8*)(&e1[(wr * 64 + bj * 16 + lr) * ESTRIDE + ks * 32 + lk * 8]);
        #pragma unroll
        for (int ai = 0; ai < 2; ++ai)
            #pragma unroll
            for (int bj = 0; bj < 4; ++bj)
                acc2[ai][bj] = __builtin_amdgcn_mfma_f32_16x16x32_bf16(wa[ai], xb[bj], acc2[ai][bj], 0, 0, 0);
    }

    float4 b2v[2];
    #pragma unroll
    for (int ai = 0; ai < 2; ++ai)
        b2v[ai] = *(const float4*)(b2 + wcc * 32 + ai * 16 + lk * 4);

    __syncthreads();   // all mm2 reads of e1 done; safe to overwrite with out-tile

    // ---- write bf16 out-tile to LDS ----
    #pragma unroll
    for (int ai = 0; ai < 2; ++ai)
        #pragma unroll
        for (int bj = 0; bj < 4; ++bj) {
            int rloc = wr * 64 + bj * 16 + lr;
            int colb = wcc * 32 + ai * 16 + lk * 4;
            ushort4 pk;
            pk.x = f2bf(silu_f(acc2[ai][bj][0] + b2v[ai].x));
            pk.y = f2bf(silu_f(acc2[ai][bj][1] + b2v[ai].y));
            pk.z = f2bf(silu_f(acc2[ai][bj][2] + b2v[ai].z));
            pk.w = f2bf(silu_f(acc2[ai][bj][3] + b2v[ai].w));
            *(ushort4*)(&e1[rloc * ESTRIDE + colb]) = pk;
        }
    __syncthreads();

    // ---- coalesced row scatter: nontemporal, keep P12 in L2/L3 ----
    {
        int rr = tid >> 5;          // 0..15
        int cl = tid & 31;          // 32 lanes cover 128 cols as f32x4
        #pragma unroll
        for (int p = 0; p < 8; ++p) {
            int r = p * 16 + rr;
            int e = sE[r];
            ushort4 pk = *(ushort4*)(&e1[r * ESTRIDE + cl * 4]);
            f32x4 o;
            o[0] = bf2f(pk.x); o[1] = bf2f(pk.y); o[2] = bf2f(pk.z); o[3] = bf2f(pk.w);
            __builtin_nontemporal_store(o, (f32x4*)(&out_edge[(size_t)e * H + cl * 4]));
        }
    }

    // ---- segmented reduction over dst runs -> sums (2 cols x 16 rows/thread) ----
    {
        int cp = (tid & 63) * 2;        // column pair
        int r0 = (tid >> 6) * 16;       // row chunk
        float a0 = 0.0f, a1 = 0.0f;
        int curn = sDst[r0];
        for (int r = r0; r < r0 + 16; ++r) {
            int n = sDst[r];
            if (n != curn) {
                atomicAdd(&sums[(size_t)curn * H + cp], a0);
                atomicAdd(&sums[(size_t)curn * H + cp + 1], a1);
                a0 = a1 = 0.0f;
                curn = n;
            }
            unsigned int u = *(const unsigned int*)(&e1[r * ESTRIDE + cp]);
            a0 += bf2f((unsigned short)(u & 0xffffu));
            a1 += bf2f((unsigned short)(u >> 16));
        }
        atomicAdd(&sums[(size_t)curn * H + cp], a0);
        atomicAdd(&sums[(size_t)curn * H + cp + 1], a1);
    }
}

// ---- node kernel: agg = sums/deg computed during staging ----
__global__ __launch_bounds__(256) void node_kernel(
    const float* __restrict__ nf, const float* __restrict__ sums,
    const int* __restrict__ cnt_i,
    const unsigned short* __restrict__ W3T, const float* __restrict__ b3,
    const unsigned short* __restrict__ W4T, const float* __restrict__ b4,
    float* __restrict__ out0)
{
    __shared__ unsigned short x_lds[64 * NSTRIDE];
    int tid = threadIdx.x;
    int nb = blockIdx.x * 64;

    // cols 0..127: nf (fp32 -> bf16)
    #pragma unroll
    for (int p = 0; p < 8; ++p) {
        int idx = p * 256 + tid;
        int n = idx >> 5, c = idx & 31;
        int node = nb + n; if (node >= NN) node = NN - 1;
        float4 v = *(const float4*)(nf + (size_t)node * H + c * 4);
        ushort4 o;
        o.x = f2bf(v.x); o.y = f2bf(v.y); o.z = f2bf(v.z); o.w = f2bf(v.w);
        *(ushort4*)(&x_lds[n * NSTRIDE + c * 4]) = o;
    }
    // cols 128..255: agg = sums/max(deg,1)
    #pragma unroll
    for (int p = 0; p < 8; ++p) {
        int idx = p * 256 + tid;
        int n = idx >> 5, c = idx & 31;
        int node = nb + n; if (node >= NN) node = NN - 1;
        float4 s = *(const float4*)(sums + (size_t)node * H + c * 4);
        float inv = 1.0f / fmaxf((float)cnt_i[node], 1.0f);
        ushort4 o;
        o.x = f2bf(s.x * inv); o.y = f2bf(s.y * inv);
        o.z = f2bf(s.z * inv); o.w = f2bf(s.w * inv);
        *(ushort4*)(&x_lds[n * NSTRIDE + 128 + c * 4]) = o;
    }
    __syncthreads();

    int wid = tid >> 6, lane = tid & 63;
    int wr = wid >> 1, wc = wid & 1;
    int lr = lane & 15, lk = lane >> 4;

    f32x4 acc[2][4];
    #pragma unroll
    for (int m = 0; m < 2; ++m)
        #pragma unroll
        for (int n = 0; n < 4; ++n) acc[m][n] = (f32x4){0.f, 0.f, 0.f, 0.f};

    #pragma unroll
    for (int ks = 0; ks < 8; ++ks) {
        bhalf8 a[2], b[4];
        #pragma unroll
        for (int m = 0; m < 2; ++m)
            a[m] = *(const bhalf8*)(&x_lds[(wr * 32 + m * 16 + lr) * NSTRIDE + ks * 32 + lk * 8]);
        #pragma unroll
        for (int n = 0; n < 4; ++n)
            b[n] = *(const bhalf8*)(W3T + (size_t)(wc * 64 + n * 16 + lr) * K3 + ks * 32 + lk * 8);
        #pragma unroll
        for (int m = 0; m < 2; ++m)
            #pragma unroll
            for (int n = 0; n < 4; ++n)
                acc[m][n] = __builtin_amdgcn_mfma_f32_16x16x32_bf16(a[m], b[n], acc[m][n], 0, 0, 0);
    }

    float bn3[4];
    #pragma unroll
    for (int n = 0; n < 4; ++n) bn3[n] = b3[wc * 64 + n * 16 + lr];

    __syncthreads();
    unsigned short* m_lds = x_lds;
    #pragma unroll
    for (int m = 0; m < 2; ++m)
        #pragma unroll
        for (int n = 0; n < 4; ++n)
            #pragma unroll
            for (int j = 0; j < 4; ++j) {
                int row = wr * 32 + m * 16 + lk * 4 + j;
                int col = wc * 64 + n * 16 + lr;
                m_lds[row * ESTRIDE + col] = f2bf(silu_f(acc[m][n][j] + bn3[n]));
            }
    __syncthreads();

    f32x4 acc2[2][4];
    #pragma unroll
    for (int m = 0; m < 2; ++m)
        #pragma unroll
        for (int n = 0; n < 4; ++n) acc2[m][n] = (f32x4){0.f, 0.f, 0.f, 0.f};

    #pragma unroll
    for (int ks = 0; ks < 4; ++ks) {
        bhalf8 a[2], b[4];
        #pragma unroll
        for (int m = 0; m < 2; ++m)
            a[m] = *(const bhalf8*)(&m_lds[(wr * 32 + m * 16 + lr) * ESTRIDE + ks * 32 + lk * 8]);
        #pragma unroll
        for (int n = 0; n < 4; ++n)
            b[n] = *(const bhalf8*)(W4T + (size_t)(wc * 64 + n * 16 + lr) * H + ks * 32 + lk * 8);
        #pragma unroll
        for (int m = 0; m < 2; ++m)
            #pragma unroll
            for (int n = 0; n < 4; ++n)
                acc2[m][n] = __builtin_amdgcn_mfma_f32_16x16x32_bf16(a[m], b[n], acc2[m][n], 0, 0, 0);
    }

    float bn4[4];
    #pragma unroll
    for (int n = 0; n < 4; ++n) bn4[n] = b4[wc * 64 + n * 16 + lr];

    #pragma unroll
    for (int m = 0; m < 2; ++m)
        #pragma unroll
        for (int n = 0; n < 4; ++n)
            #pragma unroll
            for (int j = 0; j < 4; ++j) {
                int row = wr * 32 + m * 16 + lk * 4 + j;
                int col = wc * 64 + n * 16 + lr;
                int node = nb + row;
                if (node < NN) {
                    float base = nf[(size_t)node * H + col];
                    float o = base + silu_f(acc2[m][n][j] + bn4[n]);
                    __builtin_nontemporal_store(o, &out0[(size_t)node * H + col]);
                }
            }
}

extern "C" void kernel_launch(void* const* d_in, const int* in_sizes, int n_in,
                              void* d_out, int out_size, void* d_ws, size_t ws_size,
                              hipStream_t stream) {
    const float* nf  = (const float*)d_in[0];
    const float* lat = (const float*)d_in[2];
    const float* fd  = (const float*)d_in[3];
    const float* W1  = (const float*)d_in[4];
    const float* b1  = (const float*)d_in[5];
    const float* W2  = (const float*)d_in[6];
    const float* b2  = (const float*)d_in[7];
    const float* W3  = (const float*)d_in[8];
    const float* b3  = (const float*)d_in[9];
    const float* W4  = (const float*)d_in[10];
    const float* b4  = (const float*)d_in[11];
    const int* ei    = (const int*)d_in[12];
    const int* e2g   = (const int*)d_in[13];

    float* out0     = (float*)d_out;
    float* out_edge = (float*)d_out + (size_t)NN * H;

    char* ws = (char*)d_ws;
    size_t off = 0;
    float* sums = (float*)(ws + off);                   off += (size_t)NN * H * 4;     // 25.6 MB (memset)
    int* cnt_i      = (int*)(ws + off);                 off += (size_t)NB * 256 * 4;   // (memset)
    int* fill       = (int*)(ws + off);                 off += (size_t)NB * 256 * 4;   // (memset)
    int* row_start  = (int*)(ws + off);                 off += (size_t)NB * 256 * 4;
    int* bsum       = (int*)(ws + off);                 off += 256 * 4;
    int* bbase      = (int*)(ws + off);                 off += 256 * 4;
    int* eidx       = (int*)(ws + off);                 off += (size_t)EE * 4;         // 3.2 MB
    unsigned short* P12  = (unsigned short*)(ws + off); off += (size_t)NN * 256 * 2;   // 25.6 MB
    unsigned short* W12T = (unsigned short*)(ws + off); off += (size_t)256 * H * 2;    // 64 KB
    unsigned short* W2T  = (unsigned short*)(ws + off); off += (size_t)H * H * 2;
    unsigned short* W3T  = (unsigned short*)(ws + off); off += (size_t)H * K3 * 2;
    unsigned short* W4T  = (unsigned short*)(ws + off); off += (size_t)H * H * 2;
    unsigned short* Qb   = (unsigned short*)(ws + off); off += (size_t)GG * H * 2;     // 64 KB
    const float* W1fd = W1 + (size_t)265 * H;   // fd rows of W1, used in-place

    // zero sums + cnt_i + fill (adjacent)
    (void)hipMemsetAsync(sums, 0, (size_t)NN * H * 4 + (size_t)NB * 256 * 4 * 2, stream);

    prep_kernel<<<512 + (EE + 255) / 256, 256, 0, stream>>>(
        W1, b1, W2, W3, W4, lat, ei, W12T, W2T, W3T, W4T, Qb, cnt_i);
    p12_kernel<<<(NN + 63) / 64, 256, 0, stream>>>(nf, W12T, P12);

    scan1_kernel<<<NB, 256, 0, stream>>>(cnt_i, bsum);
    scan2_kernel<<<1, 256, 0, stream>>>(bsum, bbase);
    scan3_kernel<<<NB, 256, 0, stream>>>(cnt_i, bbase, row_start);
    scatter_kernel<<<(EE + 255) / 256, 256, 0, stream>>>(ei, row_start, fill, eidx);

    edge_kernel<<<EE / 128, 512, 0, stream>>>(P12, Qb, fd, W1fd, W2T, b2,
                                              ei, e2g, eidx, out_edge, sums);
    node_kernel<<<(NN + 63) / 64, 256, 0, stream>>>(nf, sums, cnt_i, W3T, b3, W4T, b4, out0);
}

// Round 13
// 352.417 us; speedup vs baseline: 1.7403x; 1.0939x over previous
//
#include <hip/hip_runtime.h>
#include <hip/hip_bf16.h>
#include <math.h>

#define H  128
#define NN 50000
#define EE 800000
#define GG 256
#define NB 196          // ceil(NN/256)

#define K3 256
#define NSTRIDE 264     // node x-tile LDS row stride
#define ESTRIDE 136     // hidden tile LDS row stride
#define PSTRIDE 136     // p12 staging stride

typedef __attribute__((ext_vector_type(8))) short bhalf8;
typedef __attribute__((ext_vector_type(4))) float f32x4;

__device__ __forceinline__ float silu_f(float x) {
    return x * __builtin_amdgcn_rcpf(1.0f + exp2f(x * -1.442695041f));
}

// fp32 -> bf16 round-to-nearest-even
__device__ __forceinline__ unsigned short f2bf(float x) {
    unsigned int u = __float_as_uint(x);
    unsigned int r = 0x7fffu + ((u >> 16) & 1u);
    return (unsigned short)((u + r) >> 16);
}

// bf16 bits -> fp32
__device__ __forceinline__ float bf2f(unsigned short s) {
    return __uint_as_float(((unsigned int)s) << 16);
}

// ---- fast zero (replaces runtime memset node, which fills at ~100 GB/s) ----
__global__ void zero_kernel(uint4* __restrict__ p, int n16) {
    uint4 z; z.x = z.y = z.z = z.w = 0;
    for (int i = blockIdx.x * blockDim.x + threadIdx.x; i < n16; i += gridDim.x * blockDim.x)
        p[i] = z;
}

// ---- merged prep kernel: W2T/W4T/W3T/W12T/Qb + degree count ----
__global__ __launch_bounds__(256) void prep_kernel(
    const float* __restrict__ W1, const float* __restrict__ b1,
    const float* __restrict__ W2, const float* __restrict__ W3,
    const float* __restrict__ W4, const float* __restrict__ lat,
    const int* __restrict__ ei,
    unsigned short* __restrict__ W12T, unsigned short* __restrict__ W2T,
    unsigned short* __restrict__ W3T, unsigned short* __restrict__ W4T,
    unsigned short* __restrict__ Qb, int* __restrict__ cnt_i)
{
    int bid = blockIdx.x, tid = threadIdx.x;
    if (bid < 64) {
        int c = bid * 2 + (tid >> 7), k = tid & 127;
        W2T[(size_t)c * H + k] = f2bf(W2[(size_t)k * H + c]);
    } else if (bid < 128) {
        int c = (bid - 64) * 2 + (tid >> 7), k = tid & 127;
        W4T[(size_t)c * H + k] = f2bf(W4[(size_t)k * H + c]);
    } else if (bid < 256) {
        int c = bid - 128, k = tid;
        W3T[(size_t)c * K3 + k] = f2bf(W3[(size_t)k * H + c]);
    } else if (bid < 384) {
        int j = (bid - 256) * 2 + (tid >> 7), k = tid & 127;
        float v = (j < 128) ? W1[(size_t)k * H + j] : W1[(size_t)(128 + k) * H + (j - 128)];
        W12T[(size_t)j * H + k] = f2bf(v);
    } else if (bid < 512) {
        int g = (bid - 384) * 2 + (tid >> 7), c = tid & 127;
        const float* L = lat + g * 9;
        float q = b1[c];
        #pragma unroll
        for (int i = 0; i < 3; ++i)
            #pragma unroll
            for (int k = 0; k < 3; ++k) {
                float ip = L[i*3+0]*L[k*3+0] + L[i*3+1]*L[k*3+1] + L[i*3+2]*L[k*3+2];
                q += ip * W1[(size_t)(256 + i * 3 + k) * H + c];
            }
        Qb[(size_t)g * H + c] = f2bf(q);
    } else {
        int e = (bid - 512) * 256 + tid;
        if (e < EE) atomicAdd(&cnt_i[ei[EE + e]], 1);
    }
}

// P12[n][0:128] = nf[n] @ W1a ; P12[n][128:256] = nf[n] @ W1b  (bf16 out)
__global__ __launch_bounds__(256) void p12_kernel(
    const float* __restrict__ nf, const unsigned short* __restrict__ W12T,
    unsigned short* __restrict__ P12)
{
    __shared__ unsigned short x_lds[64 * PSTRIDE];
    int tid = threadIdx.x;
    int nb = blockIdx.x * 64;

    #pragma unroll
    for (int p = 0; p < 8; ++p) {
        int idx = p * 256 + tid;
        int n = idx >> 5, c = idx & 31;
        int node = nb + n; if (node >= NN) node = NN - 1;
        float4 v = *(const float4*)(nf + (size_t)node * H + c * 4);
        ushort4 o;
        o.x = f2bf(v.x); o.y = f2bf(v.y); o.z = f2bf(v.z); o.w = f2bf(v.w);
        *(ushort4*)(&x_lds[n * PSTRIDE + c * 4]) = o;
    }
    __syncthreads();

    int wid = tid >> 6, lane = tid & 63;
    int wr = wid & 1, wc = wid >> 1;       // rows wr*32.., cols wc*128..
    int lr = lane & 15, lk = lane >> 4;

    f32x4 acc[2][8];
    #pragma unroll
    for (int m = 0; m < 2; ++m)
        #pragma unroll
        for (int n = 0; n < 8; ++n) acc[m][n] = (f32x4){0.f, 0.f, 0.f, 0.f};

    #pragma unroll
    for (int ks = 0; ks < 4; ++ks) {
        bhalf8 a[2], b[8];
        #pragma unroll
        for (int m = 0; m < 2; ++m)
            a[m] = *(const bhalf8*)(&x_lds[(wr * 32 + m * 16 + lr) * PSTRIDE + ks * 32 + lk * 8]);
        #pragma unroll
        for (int n = 0; n < 8; ++n)
            b[n] = *(const bhalf8*)(W12T + (size_t)(wc * 128 + n * 16 + lr) * H + ks * 32 + lk * 8);
        #pragma unroll
        for (int m = 0; m < 2; ++m)
            #pragma unroll
            for (int n = 0; n < 8; ++n)
                acc[m][n] = __builtin_amdgcn_mfma_f32_16x16x32_bf16(a[m], b[n], acc[m][n], 0, 0, 0);
    }

    #pragma unroll
    for (int m = 0; m < 2; ++m)
        #pragma unroll
        for (int n = 0; n < 8; ++n)
            #pragma unroll
            for (int j = 0; j < 4; ++j) {
                int row = wr * 32 + m * 16 + lk * 4 + j;
                int col = wc * 128 + n * 16 + lr;
                int node = nb + row;
                if (node < NN) P12[(size_t)node * 256 + col] = f2bf(acc[m][n][j]);
            }
}

// ---- CSR build ----

__global__ void scan1_kernel(const int* __restrict__ cnt_i, int* __restrict__ bsum) {
    __shared__ int red[256];
    int b = blockIdx.x, t = threadIdx.x;
    int n = b * 256 + t;
    red[t] = (n < NN) ? cnt_i[n] : 0;
    __syncthreads();
    for (int s = 128; s > 0; s >>= 1) {
        if (t < s) red[t] += red[t + s];
        __syncthreads();
    }
    if (t == 0) bsum[b] = red[0];
}

__global__ void scan2_kernel(const int* __restrict__ bsum, int* __restrict__ bbase) {
    __shared__ int tmp[256];
    int t = threadIdx.x;
    int c = (t < NB) ? bsum[t] : 0;
    tmp[t] = c;
    __syncthreads();
    for (int s = 1; s < 256; s <<= 1) {
        int u = (t >= s) ? tmp[t - s] : 0;
        __syncthreads();
        tmp[t] += u;
        __syncthreads();
    }
    if (t < NB) bbase[t] = tmp[t] - c;   // exclusive
}

__global__ void scan3_kernel(const int* __restrict__ cnt_i, const int* __restrict__ bbase,
                             int* __restrict__ row_start) {
    __shared__ int tmp[256];
    int b = blockIdx.x, t = threadIdx.x;
    int n = b * 256 + t;
    int c = (n < NN) ? cnt_i[n] : 0;
    tmp[t] = c;
    __syncthreads();
    for (int s = 1; s < 256; s <<= 1) {
        int u = (t >= s) ? tmp[t - s] : 0;
        __syncthreads();
        tmp[t] += u;
        __syncthreads();
    }
    if (n < NN) row_start[n] = bbase[b] + tmp[t] - c;   // exclusive
}

__global__ void scatter_kernel(const int* __restrict__ ei, const int* __restrict__ row_start,
                               int* __restrict__ fill, int* __restrict__ eidx) {
    int e = blockIdx.x * blockDim.x + threadIdx.x;
    if (e < EE) {
        int d = ei[EE + e];
        int pos = row_start[d] + atomicAdd(&fill[d], 1);
        eidx[pos] = e;
    }
}

// ---- edge kernel v9: 64-edge tiles, 256 threads, 5 blocks/CU for gather overlap ----
__global__ __launch_bounds__(256, 5) void edge_kernel(
    const unsigned short* __restrict__ P12, const unsigned short* __restrict__ Qb,
    const float* __restrict__ fdg, const float* __restrict__ W1fd,
    const unsigned short* __restrict__ W2T, const float* __restrict__ b2,
    const int* __restrict__ ei, const int* __restrict__ e2g,
    const int* __restrict__ eidx,
    float* __restrict__ out_edge, float* __restrict__ sums)
{
    __shared__ unsigned short e1[64 * ESTRIDE];   // 17.4 KB; reused as out-tile (bf16)
    __shared__ int sE[64], sSrc[64], sDst[64], sG[64];
    __shared__ float sFd[64 * 3];

    int tid = threadIdx.x;
    int eb = blockIdx.x * 64;

    if (tid < 64) sE[tid] = eidx[eb + tid];
    __syncthreads();
    if (tid < 64) {
        sSrc[tid] = ei[sE[tid]];
    } else if (tid < 128) {
        sDst[tid - 64] = ei[EE + sE[tid - 64]];
    } else if (tid < 192) {
        sG[tid - 128] = e2g[sE[tid - 128]];
    } else {
        int r = tid - 192;
        int e = sE[r];
        sFd[r * 3 + 0] = fdg[(size_t)e * 3 + 0];
        sFd[r * 3 + 1] = fdg[(size_t)e * 3 + 1];
        sFd[r * 3 + 2] = fdg[(size_t)e * 3 + 2];
    }
    __syncthreads();

    int c = tid & 15;
    // per-lane W1_fd columns (3 rows x 8 cols), L1-cached
    float4 wf[3][2];
    #pragma unroll
    for (int k = 0; k < 3; ++k)
        #pragma unroll
        for (int h = 0; h < 2; ++h)
            wf[k][h] = *(const float4*)(W1fd + k * H + c * 8 + h * 4);

    // ---- prefetch all P12 gathers (8 independent 16B loads in flight) ----
    uint4 P1v[4], P2v[4];
    #pragma unroll
    for (int p = 0; p < 4; ++p) {
        int r = p * 16 + (tid >> 4);
        P1v[p] = *(const uint4*)(P12 + (size_t)sSrc[r] * 256 + c * 8);
        P2v[p] = *(const uint4*)(P12 + (size_t)sDst[r] * 256 + 128 + c * 8);
    }

    // ---- build e1[64][128] (bf16): 4 rows per thread ----
    #pragma unroll
    for (int p = 0; p < 4; ++p) {
        int r = p * 16 + (tid >> 4);
        int g = sG[r];
        bhalf8 p1 = *(const bhalf8*)(&P1v[p]);
        bhalf8 p2 = *(const bhalf8*)(&P2v[p]);
        bhalf8 qv = *(const bhalf8*)(Qb + (size_t)g * H + c * 8);
        float f0 = sFd[r * 3 + 0], f1 = sFd[r * 3 + 1], f2v = sFd[r * 3 + 2];
        unsigned int w[4];
        #pragma unroll
        for (int jj = 0; jj < 4; ++jj) {
            unsigned int lo = 0, hi = 0;
            #pragma unroll
            for (int half = 0; half < 2; ++half) {
                int j = jj * 2 + half;
                const float* wfp = (const float*)&wf[0][0];
                float wv0 = wfp[j];
                float wv1 = wfp[8 + j];
                float wv2 = wfp[16 + j];
                float v = bf2f((unsigned short)p1[j]) + bf2f((unsigned short)p2[j])
                        + bf2f((unsigned short)qv[j])
                        + f0 * wv0 + f1 * wv1 + f2v * wv2;
                unsigned int us = f2bf(silu_f(v));
                if (half == 0) lo = us; else hi = us;
            }
            w[jj] = lo | (hi << 16);
        }
        uint4 pk; pk.x = w[0]; pk.y = w[1]; pk.z = w[2]; pk.w = w[3];
        *(uint4*)(&e1[r * ESTRIDE + c * 8]) = pk;
    }
    __syncthreads();

    // ---- mm2: 4 waves, each 32 rows x 64 cols ----
    int wid = tid >> 6, lane = tid & 63;
    int wr = wid >> 1, wcc = wid & 1;   // rows wr*32.., cols wcc*64..
    int lr = lane & 15, lk = lane >> 4;

    f32x4 acc2[4][2];
    #pragma unroll
    for (int a = 0; a < 4; ++a)
        #pragma unroll
        for (int b = 0; b < 2; ++b) acc2[a][b] = (f32x4){0.f, 0.f, 0.f, 0.f};

    #pragma unroll
    for (int ks = 0; ks < 4; ++ks) {
        bhalf8 wa[4], xb[2];
        #pragma unroll
        for (int ai = 0; ai < 4; ++ai)
            wa[ai] = *(const bhalf8*)(W2T + (size_t)(wcc * 64 + ai * 16 + lr) * H + ks * 32 + lk * 8);
        #pragma unroll
        for (int bj = 0; bj < 2; ++bj)
            xb[bj] = *(const bhalf8*)(&e1[(wr * 32 + bj * 16 + lr) * ESTRIDE + ks * 32 + lk * 8]);
        #pragma unroll
        for (int ai = 0; ai < 4; ++ai)
            #pragma unroll
            for (int bj = 0; bj < 2; ++bj)
                acc2[ai][bj] = __builtin_amdgcn_mfma_f32_16x16x32_bf16(wa[ai], xb[bj], acc2[ai][bj], 0, 0, 0);
    }

    float4 b2v[4];
    #pragma unroll
    for (int ai = 0; ai < 4; ++ai)
        b2v[ai] = *(const float4*)(b2 + wcc * 64 + ai * 16 + lk * 4);

    __syncthreads();   // all mm2 reads of e1 done; safe to overwrite with out-tile

    // ---- write bf16 out-tile to LDS ----
    #pragma unroll
    for (int ai = 0; ai < 4; ++ai)
        #pragma unroll
        for (int bj = 0; bj < 2; ++bj) {
            int rloc = wr * 32 + bj * 16 + lr;
            int colb = wcc * 64 + ai * 16 + lk * 4;
            ushort4 pk;
            pk.x = f2bf(silu_f(acc2[ai][bj][0] + b2v[ai].x));
            pk.y = f2bf(silu_f(acc2[ai][bj][1] + b2v[ai].y));
            pk.z = f2bf(silu_f(acc2[ai][bj][2] + b2v[ai].z));
            pk.w = f2bf(silu_f(acc2[ai][bj][3] + b2v[ai].w));
            *(ushort4*)(&e1[rloc * ESTRIDE + colb]) = pk;
        }
    __syncthreads();

    // ---- coalesced row scatter: nontemporal, keep P12 in L2/L3 ----
    {
        int rr = tid >> 5;          // 0..7
        int cl = tid & 31;          // 32 lanes cover 128 cols as f32x4
        #pragma unroll
        for (int p = 0; p < 8; ++p) {
            int r = p * 8 + rr;
            int e = sE[r];
            ushort4 pk = *(ushort4*)(&e1[r * ESTRIDE + cl * 4]);
            f32x4 o;
            o[0] = bf2f(pk.x); o[1] = bf2f(pk.y); o[2] = bf2f(pk.z); o[3] = bf2f(pk.w);
            __builtin_nontemporal_store(o, (f32x4*)(&out_edge[(size_t)e * H + cl * 4]));
        }
    }

    // ---- segmented reduction over dst runs -> sums (2 cols x 16 rows/thread) ----
    {
        int cp = (tid & 63) * 2;        // column pair
        int r0 = (tid >> 6) * 16;       // row chunk (4 x 16 = 64 rows)
        float a0 = 0.0f, a1 = 0.0f;
        int curn = sDst[r0];
        for (int r = r0; r < r0 + 16; ++r) {
            int n = sDst[r];
            if (n != curn) {
                atomicAdd(&sums[(size_t)curn * H + cp], a0);
                atomicAdd(&sums[(size_t)curn * H + cp + 1], a1);
                a0 = a1 = 0.0f;
                curn = n;
            }
            unsigned int u = *(const unsigned int*)(&e1[r * ESTRIDE + cp]);
            a0 += bf2f((unsigned short)(u & 0xffffu));
            a1 += bf2f((unsigned short)(u >> 16));
        }
        atomicAdd(&sums[(size_t)curn * H + cp], a0);
        atomicAdd(&sums[(size_t)curn * H + cp + 1], a1);
    }
}

// ---- node kernel: agg = sums/deg computed during staging ----
__global__ __launch_bounds__(256) void node_kernel(
    const float* __restrict__ nf, const float* __restrict__ sums,
    const int* __restrict__ cnt_i,
    const unsigned short* __restrict__ W3T, const float* __restrict__ b3,
    const unsigned short* __restrict__ W4T, const float* __restrict__ b4,
    float* __restrict__ out0)
{
    __shared__ unsigned short x_lds[64 * NSTRIDE];
    int tid = threadIdx.x;
    int nb = blockIdx.x * 64;

    // cols 0..127: nf (fp32 -> bf16)
    #pragma unroll
    for (int p = 0; p < 8; ++p) {
        int idx = p * 256 + tid;
        int n = idx >> 5, c = idx & 31;
        int node = nb + n; if (node >= NN) node = NN - 1;
        float4 v = *(const float4*)(nf + (size_t)node * H + c * 4);
        ushort4 o;
        o.x = f2bf(v.x); o.y = f2bf(v.y); o.z = f2bf(v.z); o.w = f2bf(v.w);
        *(ushort4*)(&x_lds[n * NSTRIDE + c * 4]) = o;
    }
    // cols 128..255: agg = sums/max(deg,1)
    #pragma unroll
    for (int p = 0; p < 8; ++p) {
        int idx = p * 256 + tid;
        int n = idx >> 5, c = idx & 31;
        int node = nb + n; if (node >= NN) node = NN - 1;
        float4 s = *(const float4*)(sums + (size_t)node * H + c * 4);
        float inv = 1.0f / fmaxf((float)cnt_i[node], 1.0f);
        ushort4 o;
        o.x = f2bf(s.x * inv); o.y = f2bf(s.y * inv);
        o.z = f2bf(s.z * inv); o.w = f2bf(s.w * inv);
        *(ushort4*)(&x_lds[n * NSTRIDE + 128 + c * 4]) = o;
    }
    __syncthreads();

    int wid = tid >> 6, lane = tid & 63;
    int wr = wid >> 1, wc = wid & 1;
    int lr = lane & 15, lk = lane >> 4;

    f32x4 acc[2][4];
    #pragma unroll
    for (int m = 0; m < 2; ++m)
        #pragma unroll
        for (int n = 0; n < 4; ++n) acc[m][n] = (f32x4){0.f, 0.f, 0.f, 0.f};

    #pragma unroll
    for (int ks = 0; ks < 8; ++ks) {
        bhalf8 a[2], b[4];
        #pragma unroll
        for (int m = 0; m < 2; ++m)
            a[m] = *(const bhalf8*)(&x_lds[(wr * 32 + m * 16 + lr) * NSTRIDE + ks * 32 + lk * 8]);
        #pragma unroll
        for (int n = 0; n < 4; ++n)
            b[n] = *(const bhalf8*)(W3T + (size_t)(wc * 64 + n * 16 + lr) * K3 + ks * 32 + lk * 8);
        #pragma unroll
        for (int m = 0; m < 2; ++m)
            #pragma unroll
            for (int n = 0; n < 4; ++n)
                acc[m][n] = __builtin_amdgcn_mfma_f32_16x16x32_bf16(a[m], b[n], acc[m][n], 0, 0, 0);
    }

    float bn3[4];
    #pragma unroll
    for (int n = 0; n < 4; ++n) bn3[n] = b3[wc * 64 + n * 16 + lr];

    __syncthreads();
    unsigned short* m_lds = x_lds;
    #pragma unroll
    for (int m = 0; m < 2; ++m)
        #pragma unroll
        for (int n = 0; n < 4; ++n)
            #pragma unroll
            for (int j = 0; j < 4; ++j) {
                int row = wr * 32 + m * 16 + lk * 4 + j;
                int col = wc * 64 + n * 16 + lr;
                m_lds[row * ESTRIDE + col] = f2bf(silu_f(acc[m][n][j] + bn3[n]));
            }
    __syncthreads();

    f32x4 acc2[2][4];
    #pragma unroll
    for (int m = 0; m < 2; ++m)
        #pragma unroll
        for (int n = 0; n < 4; ++n) acc2[m][n] = (f32x4){0.f, 0.f, 0.f, 0.f};

    #pragma unroll
    for (int ks = 0; ks < 4; ++ks) {
        bhalf8 a[2], b[4];
        #pragma unroll
        for (int m = 0; m < 2; ++m)
            a[m] = *(const bhalf8*)(&m_lds[(wr * 32 + m * 16 + lr) * ESTRIDE + ks * 32 + lk * 8]);
        #pragma unroll
        for (int n = 0; n < 4; ++n)
            b[n] = *(const bhalf8*)(W4T + (size_t)(wc * 64 + n * 16 + lr) * H + ks * 32 + lk * 8);
        #pragma unroll
        for (int m = 0; m < 2; ++m)
            #pragma unroll
            for (int n = 0; n < 4; ++n)
                acc2[m][n] = __builtin_amdgcn_mfma_f32_16x16x32_bf16(a[m], b[n], acc2[m][n], 0, 0, 0);
    }

    float bn4[4];
    #pragma unroll
    for (int n = 0; n < 4; ++n) bn4[n] = b4[wc * 64 + n * 16 + lr];

    #pragma unroll
    for (int m = 0; m < 2; ++m)
        #pragma unroll
        for (int n = 0; n < 4; ++n)
            #pragma unroll
            for (int j = 0; j < 4; ++j) {
                int row = wr * 32 + m * 16 + lk * 4 + j;
                int col = wc * 64 + n * 16 + lr;
                int node = nb + row;
                if (node < NN) {
                    float base = nf[(size_t)node * H + col];
                    float o = base + silu_f(acc2[m][n][j] + bn4[n]);
                    __builtin_nontemporal_store(o, &out0[(size_t)node * H + col]);
                }
            }
}

extern "C" void kernel_launch(void* const* d_in, const int* in_sizes, int n_in,
                              void* d_out, int out_size, void* d_ws, size_t ws_size,
                              hipStream_t stream) {
    const float* nf  = (const float*)d_in[0];
    const float* lat = (const float*)d_in[2];
    const float* fd  = (const float*)d_in[3];
    const float* W1  = (const float*)d_in[4];
    const float* b1  = (const float*)d_in[5];
    const float* W2  = (const float*)d_in[6];
    const float* b2  = (const float*)d_in[7];
    const float* W3  = (const float*)d_in[8];
    const float* b3  = (const float*)d_in[9];
    const float* W4  = (const float*)d_in[10];
    const float* b4  = (const float*)d_in[11];
    const int* ei    = (const int*)d_in[12];
    const int* e2g   = (const int*)d_in[13];

    float* out0     = (float*)d_out;
    float* out_edge = (float*)d_out + (size_t)NN * H;

    char* ws = (char*)d_ws;
    size_t off = 0;
    float* sums = (float*)(ws + off);                   off += (size_t)NN * H * 4;     // 25.6 MB (zeroed)
    int* cnt_i      = (int*)(ws + off);                 off += (size_t)NB * 256 * 4;   // (zeroed)
    int* fill       = (int*)(ws + off);                 off += (size_t)NB * 256 * 4;   // (zeroed)
    int* row_start  = (int*)(ws + off);                 off += (size_t)NB * 256 * 4;
    int* bsum       = (int*)(ws + off);                 off += 256 * 4;
    int* bbase      = (int*)(ws + off);                 off += 256 * 4;
    int* eidx       = (int*)(ws + off);                 off += (size_t)EE * 4;         // 3.2 MB
    unsigned short* P12  = (unsigned short*)(ws + off); off += (size_t)NN * 256 * 2;   // 25.6 MB
    unsigned short* W12T = (unsigned short*)(ws + off); off += (size_t)256 * H * 2;    // 64 KB
    unsigned short* W2T  = (unsigned short*)(ws + off); off += (size_t)H * H * 2;
    unsigned short* W3T  = (unsigned short*)(ws + off); off += (size_t)H * K3 * 2;
    unsigned short* W4T  = (unsigned short*)(ws + off); off += (size_t)H * H * 2;
    unsigned short* Qb   = (unsigned short*)(ws + off); off += (size_t)GG * H * 2;     // 64 KB
    const float* W1fd = W1 + (size_t)265 * H;   // fd rows of W1, used in-place

    // zero sums + cnt_i + fill (adjacent, 16B-aligned sizes) with full-grid kernel
    int n16 = (int)(((size_t)NN * H * 4 + (size_t)NB * 256 * 4 * 2) / 16);
    zero_kernel<<<2048, 256, 0, stream>>>((uint4*)sums, n16);

    prep_kernel<<<512 + (EE + 255) / 256, 256, 0, stream>>>(
        W1, b1, W2, W3, W4, lat, ei, W12T, W2T, W3T, W4T, Qb, cnt_i);
    p12_kernel<<<(NN + 63) / 64, 256, 0, stream>>>(nf, W12T, P12);

    scan1_kernel<<<NB, 256, 0, stream>>>(cnt_i, bsum);
    scan2_kernel<<<1, 256, 0, stream>>>(bsum, bbase);
    scan3_kernel<<<NB, 256, 0, stream>>>(cnt_i, bbase, row_start);
    scatter_kernel<<<(EE + 255) / 256, 256, 0, stream>>>(ei, row_start, fill, eidx);

    edge_kernel<<<EE / 64, 256, 0, stream>>>(P12, Qb, fd, W1fd, W2T, b2,
                                             ei, e2g, eidx, out_edge, sums);
    node_kernel<<<(NN + 63) / 64, 256, 0, stream>>>(nf, sums, cnt_i, W3T, b3, W4T, b4, out0);
}